// Round 1
// baseline (2300.363 us; speedup 1.0000x reference)
//
#include <hip/hip_runtime.h>
#include <hip/hip_bf16.h>
#include <stdint.h>

#define B_SZ 8
#define L_SZ 2048
#define DM 768
#define DI 1536
#define DS 16
#define DR 48
#define M_SZ (B_SZ * L_SZ)   // 16384
#define N1 (2 * DI)          // 3072

typedef short short8 __attribute__((ext_vector_type(8)));
typedef float f32x4 __attribute__((ext_vector_type(4)));

__device__ __forceinline__ ushort f2b(float f) {
  __hip_bfloat16 h = __float2bfloat16(f);
  return *reinterpret_cast<ushort*>(&h);
}
__device__ __forceinline__ float b2f(ushort u) {
  __hip_bfloat16 h;
  *reinterpret_cast<ushort*>(&h) = u;
  return __bfloat162float(h);
}

// ---------------- prep kernels ----------------

__global__ __launch_bounds__(256) void cast_hidden(const float4* __restrict__ in,
                                                   ushort4* __restrict__ out, int n4) {
  int i = blockIdx.x * 256 + threadIdx.x;
  int stride = gridDim.x * 256;
  for (; i < n4; i += stride) {
    float4 v = in[i];
    ushort4 o;
    o.x = f2b(v.x); o.y = f2b(v.y); o.z = f2b(v.z); o.w = f2b(v.w);
    out[i] = o;
  }
}

// W_in (768 x 3072) -> Wt1 bf16 (3072 x 768)
__global__ __launch_bounds__(256) void transpose_w(const float* __restrict__ w,
                                                   ushort* __restrict__ wt) {
  int idx = blockIdx.x * 256 + threadIdx.x;  // 3072 * 96
  if (idx >= 3072 * 96) return;
  int n = idx % 3072;
  int kb = (idx / 3072) * 8;
  short8 o;
#pragma unroll
  for (int j = 0; j < 8; ++j) o[j] = (short)f2b(w[(size_t)(kb + j) * 3072 + n]);
  *(short8*)(wt + (size_t)n * DM + kb) = o;
}

// casts W_x (80x1536) -> bf16 ; W_dt (1536x48) -> bf16 zero-padded to (1536x64)
__global__ __launch_bounds__(256) void prep_small(const float* __restrict__ wx_f,
                                                  const float* __restrict__ wdt_f,
                                                  ushort* __restrict__ wx_b,
                                                  ushort* __restrict__ wdt_p) {
  int idx = blockIdx.x * 256 + threadIdx.x;
  const int nwx = 80 * DI;
  const int nwdt = DI * 64;
  if (idx < nwx) {
    wx_b[idx] = f2b(wx_f[idx]);
  } else if (idx < nwx + nwdt) {
    int j = idx - nwx;
    int col = j >> 6, k = j & 63;
    wdt_p[j] = (k < DR) ? f2b(wdt_f[col * DR + k]) : (ushort)0;
  }
}

// ---------------- main GEMM: xz = A1(16384x768) @ W_in, split into x / res ----------------

__global__ __launch_bounds__(256) void gemm_xz(const ushort* __restrict__ A,
                                               const ushort* __restrict__ Bt,
                                               ushort* __restrict__ xout,
                                               ushort* __restrict__ resout) {
  __shared__ short As[128 * 64];
  __shared__ short Bs[128 * 64];
  const int t = threadIdx.x;
  const int lane = t & 63;
  const int wid = t >> 6;
  const int wm = wid >> 1, wn = wid & 1;
  const int bm = blockIdx.x * 128;
  const int bn = blockIdx.y * 128;
  const int r = lane & 15, hi = lane >> 4;

  f32x4 acc[4][4];
#pragma unroll
  for (int m = 0; m < 4; ++m)
#pragma unroll
    for (int n = 0; n < 4; ++n) acc[m][n] = f32x4{0.f, 0.f, 0.f, 0.f};

  for (int k0 = 0; k0 < DM; k0 += 64) {
    __syncthreads();
#pragma unroll
    for (int p = 0; p < 4; ++p) {
      int e = p * 256 + t;
      int rr = e >> 3;
      int kb = e & 7;
      int sw = ((kb ^ (rr & 7)) << 3);
      *(short8*)&As[rr * 64 + sw] = *(const short8*)(A + (size_t)(bm + rr) * DM + k0 + kb * 8);
      *(short8*)&Bs[rr * 64 + sw] = *(const short8*)(Bt + (size_t)(bn + rr) * DM + k0 + kb * 8);
    }
    __syncthreads();
#pragma unroll
    for (int kk = 0; kk < 2; ++kk) {
      short8 af[4], bf_[4];
#pragma unroll
      for (int m = 0; m < 4; ++m) {
        int row = wm * 64 + m * 16 + r;
        af[m] = *(const short8*)&As[row * 64 + (((kk * 4 + hi) ^ (r & 7)) << 3)];
      }
#pragma unroll
      for (int n = 0; n < 4; ++n) {
        int row = wn * 64 + n * 16 + r;
        bf_[n] = *(const short8*)&Bs[row * 64 + (((kk * 4 + hi) ^ (r & 7)) << 3)];
      }
#pragma unroll
      for (int m = 0; m < 4; ++m)
#pragma unroll
        for (int n = 0; n < 4; ++n)
          acc[m][n] = __builtin_amdgcn_mfma_f32_16x16x32_bf16(af[m], bf_[n], acc[m][n], 0, 0, 0);
    }
  }

  const bool isx = (bn < DI);
  ushort* outp = isx ? xout : resout;
  const int cbase = bn - (isx ? 0 : DI) + wn * 64;
#pragma unroll
  for (int m = 0; m < 4; ++m)
#pragma unroll
    for (int n = 0; n < 4; ++n) {
      int col = cbase + n * 16 + r;
#pragma unroll
      for (int j = 0; j < 4; ++j) {
        int row = bm + wm * 64 + m * 16 + hi * 4 + j;
        outp[(size_t)row * DI + col] = f2b(acc[m][n][j]);
      }
    }
}

// ---------------- depthwise causal conv (K=4) + SiLU ----------------

__global__ __launch_bounds__(256) void conv_silu(const ushort* __restrict__ xp,
                                                 const float* __restrict__ cw,
                                                 const float* __restrict__ cb,
                                                 ushort* __restrict__ xc) {
  long long idx = (long long)blockIdx.x * 256 + threadIdx.x;
  const long long total = (long long)M_SZ * DI;
  if (idx >= total) return;
  int d = (int)(idx % DI);
  long long row = idx / DI;
  int l = (int)(row % L_SZ);
  float acc = cb[d];
#pragma unroll
  for (int k = 0; k < 4; ++k) {
    int ll = l - 3 + k;
    if (ll >= 0) acc += b2f(xp[idx + (long long)(k - 3) * DI]) * cw[d * 4 + k];
  }
  float s = acc / (1.f + __expf(-acc));
  xc[idx] = f2b(s);
}

// ---------------- x_dbl = xconv(16384x1536) @ W_x^T  ->  (16384x80) fp32 ----------------

__global__ __launch_bounds__(256) void xdbl_gemm(const ushort* __restrict__ xc,
                                                 const ushort* __restrict__ wx,
                                                 float* __restrict__ xd) {
  int wave = blockIdx.x * 4 + (threadIdx.x >> 6);
  int lane = threadIdx.x & 63;
  int r = lane & 15, hi = lane >> 4;
  int row0 = wave * 16;
  f32x4 acc[5];
#pragma unroll
  for (int n = 0; n < 5; ++n) acc[n] = f32x4{0.f, 0.f, 0.f, 0.f};
  for (int k0 = 0; k0 < DI; k0 += 32) {
    short8 a = *(const short8*)(xc + (size_t)(row0 + r) * DI + k0 + hi * 8);
#pragma unroll
    for (int n = 0; n < 5; ++n) {
      short8 b = *(const short8*)(wx + (size_t)(n * 16 + r) * DI + k0 + hi * 8);
      acc[n] = __builtin_amdgcn_mfma_f32_16x16x32_bf16(a, b, acc[n], 0, 0, 0);
    }
  }
#pragma unroll
  for (int n = 0; n < 5; ++n)
#pragma unroll
    for (int j = 0; j < 4; ++j)
      xd[(size_t)(row0 + hi * 4 + j) * 80 + n * 16 + r] = acc[n][j];
}

// ---------------- dt = softplus(x_dbl[:, :48] @ W_dt^T + b_dt)  fp32 (16384x1536) --------

__device__ __forceinline__ short8 pack8f(const float* p) {
  short8 v;
#pragma unroll
  for (int i = 0; i < 8; ++i) v[i] = (short)f2b(p[i]);
  return v;
}

__global__ __launch_bounds__(256) void dt_gemm(const float* __restrict__ xd,
                                               const ushort* __restrict__ wdtp,
                                               const float* __restrict__ bdt,
                                               float* __restrict__ dt) {
  int wave = blockIdx.x * 4 + (threadIdx.x >> 6);
  int lane = threadIdx.x & 63;
  int r = lane & 15, hi = lane >> 4;
  int row0 = wave * 16;

  float atmp[8];
  const float* ap = xd + (size_t)(row0 + r) * 80 + hi * 8;
#pragma unroll
  for (int i = 0; i < 8; ++i) atmp[i] = ap[i];
  short8 a0 = pack8f(atmp);
  short8 a1;
#pragma unroll
  for (int i = 0; i < 8; ++i) a1[i] = 0;
  if (hi < 2) {
    const float* ap1 = xd + (size_t)(row0 + r) * 80 + 32 + hi * 8;
#pragma unroll
    for (int i = 0; i < 8; ++i) atmp[i] = ap1[i];
    a1 = pack8f(atmp);
  }

  for (int nb = 0; nb < 24; ++nb) {
    int c0 = nb * 64;
    f32x4 acc[4];
#pragma unroll
    for (int n = 0; n < 4; ++n) acc[n] = f32x4{0.f, 0.f, 0.f, 0.f};
#pragma unroll
    for (int n = 0; n < 4; ++n) {
      const ushort* wp = wdtp + (size_t)(c0 + n * 16 + r) * 64;
      short8 b0 = *(const short8*)(wp + hi * 8);
      short8 b1 = *(const short8*)(wp + 32 + hi * 8);
      acc[n] = __builtin_amdgcn_mfma_f32_16x16x32_bf16(a0, b0, acc[n], 0, 0, 0);
      acc[n] = __builtin_amdgcn_mfma_f32_16x16x32_bf16(a1, b1, acc[n], 0, 0, 0);
    }
#pragma unroll
    for (int n = 0; n < 4; ++n)
#pragma unroll
      for (int j = 0; j < 4; ++j) {
        int col = c0 + n * 16 + r;
        float z = acc[n][j] + bdt[col];
        float sp = (z > 20.f) ? z : log1pf(__expf(z));
        dt[(size_t)(row0 + hi * 4 + j) * DI + col] = sp;
      }
  }
}

// ---------------- selective scan + output epilogue ----------------

__global__ __launch_bounds__(256) void scan_kernel(const float* __restrict__ dt,
                                                   const ushort* __restrict__ xc,
                                                   const float* __restrict__ xd,
                                                   const ushort* __restrict__ resb,
                                                   const float* __restrict__ A_log,
                                                   const float* __restrict__ Dp,
                                                   float* __restrict__ out) {
  int tid = blockIdx.x * 256 + threadIdx.x;
  int s = tid & 15;
  int g = tid >> 4;  // (b, d)
  int d = g % DI;
  int b = g / DI;

  float As = -__expf(A_log[d * DS + s]);
  float Dpv = Dp[d];
  float h = 0.f;

  const float* dtp = dt + (size_t)b * L_SZ * DI + d;
  const ushort* xcp = xc + (size_t)b * L_SZ * DI + d;
  const ushort* rp = resb + (size_t)b * L_SZ * DI + d;
  const float* xb = xd + (size_t)b * L_SZ * 80;
  float* op = out + (size_t)b * L_SZ * DI + d;

#pragma unroll 2
  for (int t = 0; t < L_SZ; ++t) {
    float dtv = dtp[(size_t)t * DI];
    float xv = b2f(xcp[(size_t)t * DI]);
    float Bv = xb[t * 80 + DR + s];
    float Cv = xb[t * 80 + DR + DS + s];
    float dA = __expf(dtv * As);
    h = dA * h + (dtv * xv) * Bv;
    float p = h * Cv;
    p += __shfl_xor(p, 1);
    p += __shfl_xor(p, 2);
    p += __shfl_xor(p, 4);
    p += __shfl_xor(p, 8);
    if (s == 0) {
      float rv = b2f(rp[(size_t)t * DI]);
      float yv = p + xv * Dpv;
      op[(size_t)t * DI] = yv * (rv / (1.f + __expf(-rv)));
    }
  }
}

// ---------------- launch ----------------

extern "C" void kernel_launch(void* const* d_in, const int* in_sizes, int n_in,
                              void* d_out, int out_size, void* d_ws, size_t ws_size,
                              hipStream_t stream) {
  const float* hs     = (const float*)d_in[0];
  const float* W_in   = (const float*)d_in[1];
  const float* conv_w = (const float*)d_in[2];
  const float* conv_b = (const float*)d_in[3];
  const float* W_x    = (const float*)d_in[4];
  const float* W_dt   = (const float*)d_in[5];
  const float* b_dt   = (const float*)d_in[6];
  const float* A_log  = (const float*)d_in[7];
  const float* D_par  = (const float*)d_in[8];
  float* out = (float*)d_out;
  char* ws = (char*)d_ws;

  // workspace layout (bytes)
  size_t o = 0;
  ushort* A1   = (ushort*)(ws + o); o += (size_t)M_SZ * DM * 2;        // 25.2 MB
  ushort* Wt1  = (ushort*)(ws + o); o += (size_t)N1 * DM * 2;          // 4.7 MB
  ushort* Wxb  = (ushort*)(ws + o); o += (size_t)80 * DI * 2;          // 0.25 MB
  ushort* Wdtp = (ushort*)(ws + o); o += (size_t)DI * 64 * 2;          // 0.2 MB
  ushort* xpre = (ushort*)(ws + o); o += (size_t)M_SZ * DI * 2;        // 50.3 MB
  ushort* resb = (ushort*)(ws + o); o += (size_t)M_SZ * DI * 2;        // 50.3 MB
  ushort* xcv  = (ushort*)(ws + o); o += (size_t)M_SZ * DI * 2;        // 50.3 MB
  float*  xdbl = (float*)(ws + o);  o += (size_t)M_SZ * 80 * 4;        // 5.2 MB
  float*  dtb  = (float*)(ws + o);  o += (size_t)M_SZ * DI * 4;        // 100.7 MB
  if (ws_size < o) return;  // clean fail instead of OOB

  int n4 = M_SZ * DM / 4;
  cast_hidden<<<dim3((n4 + 255) / 256), dim3(256), 0, stream>>>((const float4*)hs, (ushort4*)A1, n4);
  transpose_w<<<dim3((3072 * 96 + 255) / 256), dim3(256), 0, stream>>>(W_in, Wt1);
  prep_small<<<dim3((80 * DI + DI * 64 + 255) / 256), dim3(256), 0, stream>>>(W_x, W_dt, Wxb, Wdtp);

  gemm_xz<<<dim3(M_SZ / 128, N1 / 128), dim3(256), 0, stream>>>(A1, Wt1, xpre, resb);

  conv_silu<<<dim3((M_SZ * DI) / 256), dim3(256), 0, stream>>>(xpre, conv_w, conv_b, xcv);

  xdbl_gemm<<<dim3(M_SZ / 64), dim3(256), 0, stream>>>(xcv, Wxb, xdbl);

  dt_gemm<<<dim3(M_SZ / 64), dim3(256), 0, stream>>>(xdbl, Wdtp, b_dt, dtb);

  scan_kernel<<<dim3(B_SZ * DI * DS / 256), dim3(256), 0, stream>>>(dtb, xcv, xdbl, resb,
                                                                    A_log, D_par, out);
}

// Round 2
// 645.582 us; speedup vs baseline: 3.5632x; 3.5632x over previous
//
#include <hip/hip_runtime.h>
#include <hip/hip_bf16.h>
#include <stdint.h>

#define B_SZ 8
#define L_SZ 2048
#define DM 768
#define DI 1536
#define DS 16
#define DR 48
#define M_SZ (B_SZ * L_SZ)   // 16384
#define N1 (2 * DI)          // 3072

#define NC 32                 // chunks per sequence
#define TC (L_SZ / NC)        // 64 steps per chunk
#define CH (B_SZ * DI)        // 12288 channels

typedef short short8 __attribute__((ext_vector_type(8)));
typedef float f32x4 __attribute__((ext_vector_type(4)));

__device__ __forceinline__ ushort f2b(float f) {
  __hip_bfloat16 h = __float2bfloat16(f);
  return *reinterpret_cast<ushort*>(&h);
}
__device__ __forceinline__ float b2f(ushort u) {
  __hip_bfloat16 h;
  *reinterpret_cast<ushort*>(&h) = u;
  return __bfloat162float(h);
}

// ---------------- prep kernels ----------------

__global__ __launch_bounds__(256) void cast_hidden(const float4* __restrict__ in,
                                                   ushort4* __restrict__ out, int n4) {
  int i = blockIdx.x * 256 + threadIdx.x;
  int stride = gridDim.x * 256;
  for (; i < n4; i += stride) {
    float4 v = in[i];
    ushort4 o;
    o.x = f2b(v.x); o.y = f2b(v.y); o.z = f2b(v.z); o.w = f2b(v.w);
    out[i] = o;
  }
}

// W_in (768 x 3072) -> Wt1 bf16 (3072 x 768)
__global__ __launch_bounds__(256) void transpose_w(const float* __restrict__ w,
                                                   ushort* __restrict__ wt) {
  int idx = blockIdx.x * 256 + threadIdx.x;  // 3072 * 96
  if (idx >= 3072 * 96) return;
  int n = idx % 3072;
  int kb = (idx / 3072) * 8;
  short8 o;
#pragma unroll
  for (int j = 0; j < 8; ++j) o[j] = (short)f2b(w[(size_t)(kb + j) * 3072 + n]);
  *(short8*)(wt + (size_t)n * DM + kb) = o;
}

// casts W_x (80x1536) -> bf16 ; W_dt (1536x48) -> bf16 zero-padded to (1536x64)
__global__ __launch_bounds__(256) void prep_small(const float* __restrict__ wx_f,
                                                  const float* __restrict__ wdt_f,
                                                  ushort* __restrict__ wx_b,
                                                  ushort* __restrict__ wdt_p) {
  int idx = blockIdx.x * 256 + threadIdx.x;
  const int nwx = 80 * DI;
  const int nwdt = DI * 64;
  if (idx < nwx) {
    wx_b[idx] = f2b(wx_f[idx]);
  } else if (idx < nwx + nwdt) {
    int j = idx - nwx;
    int col = j >> 6, k = j & 63;
    wdt_p[j] = (k < DR) ? f2b(wdt_f[col * DR + k]) : (ushort)0;
  }
}

// ---------------- main GEMM: xz = A1(16384x768) @ W_in, split into x / res ----------------

__global__ __launch_bounds__(256) void gemm_xz(const ushort* __restrict__ A,
                                               const ushort* __restrict__ Bt,
                                               ushort* __restrict__ xout,
                                               ushort* __restrict__ resout) {
  __shared__ short As[128 * 64];
  __shared__ short Bs[128 * 64];
  const int t = threadIdx.x;
  const int lane = t & 63;
  const int wid = t >> 6;
  const int wm = wid >> 1, wn = wid & 1;
  const int bm = blockIdx.x * 128;
  const int bn = blockIdx.y * 128;
  const int r = lane & 15, hi = lane >> 4;

  f32x4 acc[4][4];
#pragma unroll
  for (int m = 0; m < 4; ++m)
#pragma unroll
    for (int n = 0; n < 4; ++n) acc[m][n] = f32x4{0.f, 0.f, 0.f, 0.f};

  for (int k0 = 0; k0 < DM; k0 += 64) {
    __syncthreads();
#pragma unroll
    for (int p = 0; p < 4; ++p) {
      int e = p * 256 + t;
      int rr = e >> 3;
      int kb = e & 7;
      int sw = ((kb ^ (rr & 7)) << 3);
      *(short8*)&As[rr * 64 + sw] = *(const short8*)(A + (size_t)(bm + rr) * DM + k0 + kb * 8);
      *(short8*)&Bs[rr * 64 + sw] = *(const short8*)(Bt + (size_t)(bn + rr) * DM + k0 + kb * 8);
    }
    __syncthreads();
#pragma unroll
    for (int kk = 0; kk < 2; ++kk) {
      short8 af[4], bf_[4];
#pragma unroll
      for (int m = 0; m < 4; ++m) {
        int row = wm * 64 + m * 16 + r;
        af[m] = *(const short8*)&As[row * 64 + (((kk * 4 + hi) ^ (r & 7)) << 3)];
      }
#pragma unroll
      for (int n = 0; n < 4; ++n) {
        int row = wn * 64 + n * 16 + r;
        bf_[n] = *(const short8*)&Bs[row * 64 + (((kk * 4 + hi) ^ (r & 7)) << 3)];
      }
#pragma unroll
      for (int m = 0; m < 4; ++m)
#pragma unroll
        for (int n = 0; n < 4; ++n)
          acc[m][n] = __builtin_amdgcn_mfma_f32_16x16x32_bf16(af[m], bf_[n], acc[m][n], 0, 0, 0);
    }
  }

  const bool isx = (bn < DI);
  ushort* outp = isx ? xout : resout;
  const int cbase = bn - (isx ? 0 : DI) + wn * 64;
#pragma unroll
  for (int m = 0; m < 4; ++m)
#pragma unroll
    for (int n = 0; n < 4; ++n) {
      int col = cbase + n * 16 + r;
#pragma unroll
      for (int j = 0; j < 4; ++j) {
        int row = bm + wm * 64 + m * 16 + hi * 4 + j;
        outp[(size_t)row * DI + col] = f2b(acc[m][n][j]);
      }
    }
}

// ---------------- depthwise causal conv (K=4) + SiLU ----------------

__global__ __launch_bounds__(256) void conv_silu(const ushort* __restrict__ xp,
                                                 const float* __restrict__ cw,
                                                 const float* __restrict__ cb,
                                                 ushort* __restrict__ xc) {
  long long idx = (long long)blockIdx.x * 256 + threadIdx.x;
  const long long total = (long long)M_SZ * DI;
  if (idx >= total) return;
  int d = (int)(idx % DI);
  long long row = idx / DI;
  int l = (int)(row % L_SZ);
  float acc = cb[d];
#pragma unroll
  for (int k = 0; k < 4; ++k) {
    int ll = l - 3 + k;
    if (ll >= 0) acc += b2f(xp[idx + (long long)(k - 3) * DI]) * cw[d * 4 + k];
  }
  float s = acc / (1.f + __expf(-acc));
  xc[idx] = f2b(s);
}

// ---------------- x_dbl = xconv(16384x1536) @ W_x^T  ->  (16384x80) fp32 ----------------

__global__ __launch_bounds__(256) void xdbl_gemm(const ushort* __restrict__ xc,
                                                 const ushort* __restrict__ wx,
                                                 float* __restrict__ xd) {
  int wave = blockIdx.x * 4 + (threadIdx.x >> 6);
  int lane = threadIdx.x & 63;
  int r = lane & 15, hi = lane >> 4;
  int row0 = wave * 16;
  f32x4 acc[5];
#pragma unroll
  for (int n = 0; n < 5; ++n) acc[n] = f32x4{0.f, 0.f, 0.f, 0.f};
  for (int k0 = 0; k0 < DI; k0 += 32) {
    short8 a = *(const short8*)(xc + (size_t)(row0 + r) * DI + k0 + hi * 8);
#pragma unroll
    for (int n = 0; n < 5; ++n) {
      short8 b = *(const short8*)(wx + (size_t)(n * 16 + r) * DI + k0 + hi * 8);
      acc[n] = __builtin_amdgcn_mfma_f32_16x16x32_bf16(a, b, acc[n], 0, 0, 0);
    }
  }
#pragma unroll
  for (int n = 0; n < 5; ++n)
#pragma unroll
    for (int j = 0; j < 4; ++j)
      xd[(size_t)(row0 + hi * 4 + j) * 80 + n * 16 + r] = acc[n][j];
}

// ---------------- dt = softplus(x_dbl[:, :48] @ W_dt^T + b_dt)  fp32 (16384x1536) --------

__device__ __forceinline__ short8 pack8f(const float* p) {
  short8 v;
#pragma unroll
  for (int i = 0; i < 8; ++i) v[i] = (short)f2b(p[i]);
  return v;
}

__global__ __launch_bounds__(256) void dt_gemm(const float* __restrict__ xd,
                                               const ushort* __restrict__ wdtp,
                                               const float* __restrict__ bdt,
                                               float* __restrict__ dt) {
  int wave = blockIdx.x * 4 + (threadIdx.x >> 6);
  int lane = threadIdx.x & 63;
  int r = lane & 15, hi = lane >> 4;
  int row0 = wave * 16;

  float atmp[8];
  const float* ap = xd + (size_t)(row0 + r) * 80 + hi * 8;
#pragma unroll
  for (int i = 0; i < 8; ++i) atmp[i] = ap[i];
  short8 a0 = pack8f(atmp);
  short8 a1;
#pragma unroll
  for (int i = 0; i < 8; ++i) a1[i] = 0;
  if (hi < 2) {
    const float* ap1 = xd + (size_t)(row0 + r) * 80 + 32 + hi * 8;
#pragma unroll
    for (int i = 0; i < 8; ++i) atmp[i] = ap1[i];
    a1 = pack8f(atmp);
  }

  for (int nb = 0; nb < 24; ++nb) {
    int c0 = nb * 64;
    f32x4 acc[4];
#pragma unroll
    for (int n = 0; n < 4; ++n) acc[n] = f32x4{0.f, 0.f, 0.f, 0.f};
#pragma unroll
    for (int n = 0; n < 4; ++n) {
      const ushort* wp = wdtp + (size_t)(c0 + n * 16 + r) * 64;
      short8 b0 = *(const short8*)(wp + hi * 8);
      short8 b1 = *(const short8*)(wp + 32 + hi * 8);
      acc[n] = __builtin_amdgcn_mfma_f32_16x16x32_bf16(a0, b0, acc[n], 0, 0, 0);
      acc[n] = __builtin_amdgcn_mfma_f32_16x16x32_bf16(a1, b1, acc[n], 0, 0, 0);
    }
#pragma unroll
    for (int n = 0; n < 4; ++n)
#pragma unroll
      for (int j = 0; j < 4; ++j) {
        int col = c0 + n * 16 + r;
        float z = acc[n][j] + bdt[col];
        float sp = (z > 20.f) ? z : log1pf(__expf(z));
        dt[(size_t)(row0 + hi * 4 + j) * DI + col] = sp;
      }
  }
}

// ---------------- chunked selective scan ----------------
// pass 1: per-chunk local scan from h=0; emit h_end[16] and sum(dt)

__global__ __launch_bounds__(256) void scan_pass1(const float* __restrict__ dt,
                                                  const ushort* __restrict__ xc,
                                                  const float* __restrict__ xd,
                                                  const float* __restrict__ A_log,
                                                  float* __restrict__ hend,
                                                  float* __restrict__ sumdt) {
  const int d = blockIdx.x * 256 + threadIdx.x;
  const int c = blockIdx.y, b = blockIdx.z;
  const int t0 = c * TC;

  __shared__ float Bs[TC * 16];  // 4 KB
  for (int i = threadIdx.x; i < TC * 16; i += 256) {
    int tt = i >> 4, s = i & 15;
    Bs[i] = xd[((size_t)(b * L_SZ + t0 + tt)) * 80 + DR + s];
  }

  float As2[16];
#pragma unroll
  for (int s = 0; s < 16; ++s)
    As2[s] = -__expf(A_log[d * DS + s]) * 1.44269504088896f;  // A * log2(e)

  __syncthreads();

  float h[16];
#pragma unroll
  for (int s = 0; s < 16; ++s) h[s] = 0.f;
  float sd = 0.f;

  const float* dtp = dt + ((size_t)b * L_SZ + t0) * DI + d;
  const ushort* xp = xc + ((size_t)b * L_SZ + t0) * DI + d;

  float dtv_n = dtp[0];
  ushort xu_n = xp[0];
  for (int tt = 0; tt < TC; ++tt) {
    float dtv = dtv_n;
    ushort xu = xu_n;
    // depth-1 prefetch (one-past-end lands in adjacent ws buffers, harmless)
    dtv_n = dtp[(size_t)(tt + 1) * DI];
    xu_n = xp[(size_t)(tt + 1) * DI];
    float xv = b2f(xu);
    sd += dtv;
    float dx = dtv * xv;
    const float* bp = &Bs[tt * 16];
#pragma unroll
    for (int s = 0; s < 16; ++s) {
      float arg = dtv * As2[s];
      float dA;
      asm("v_exp_f32 %0, %1" : "=v"(dA) : "v"(arg));  // 2^arg = exp(dt*A)
      h[s] = dA * h[s] + dx * bp[s];
    }
  }

  const size_t ch = (size_t)b * DI + d;
  sumdt[ch * NC + c] = sd;
  float4* hp = (float4*)&hend[((size_t)c * CH + ch) * 16];
#pragma unroll
  for (int q = 0; q < 4; ++q)
    hp[q] = make_float4(h[q * 4], h[q * 4 + 1], h[q * 4 + 2], h[q * 4 + 3]);
}

// pass 2: combine chunk transitions -> h_start per chunk

__global__ __launch_bounds__(256) void scan_pass2(const float* __restrict__ A_log,
                                                  const float* __restrict__ sumdt,
                                                  const float* __restrict__ hend,
                                                  float* __restrict__ hstart) {
  int idx = blockIdx.x * 256 + threadIdx.x;  // ch*16 + s
  int ch = idx >> 4, s = idx & 15;
  int d = ch % DI;
  float A = -__expf(A_log[d * DS + s]);
  float h = 0.f;
  for (int c = 0; c < NC; ++c) {
    hstart[((size_t)c * CH + ch) * 16 + s] = h;
    float sd = sumdt[(size_t)ch * NC + c];
    h = __expf(A * sd) * h + hend[((size_t)c * CH + ch) * 16 + s];
  }
}

// pass 3: re-run scan with correct h_start, fused epilogue

__global__ __launch_bounds__(256) void scan_pass3(const float* __restrict__ dt,
                                                  const ushort* __restrict__ xc,
                                                  const float* __restrict__ xd,
                                                  const ushort* __restrict__ resb,
                                                  const float* __restrict__ A_log,
                                                  const float* __restrict__ Dp,
                                                  const float* __restrict__ hstart,
                                                  float* __restrict__ out) {
  const int d = blockIdx.x * 256 + threadIdx.x;
  const int c = blockIdx.y, b = blockIdx.z;
  const int t0 = c * TC;

  __shared__ float Bs[TC * 16];  // 4 KB
  __shared__ float Cs[TC * 16];  // 4 KB
  for (int i = threadIdx.x; i < TC * 16; i += 256) {
    int tt = i >> 4, s = i & 15;
    size_t row = ((size_t)(b * L_SZ + t0 + tt)) * 80;
    Bs[i] = xd[row + DR + s];
    Cs[i] = xd[row + DR + DS + s];
  }

  float As2[16];
#pragma unroll
  for (int s = 0; s < 16; ++s)
    As2[s] = -__expf(A_log[d * DS + s]) * 1.44269504088896f;
  const float Dpv = Dp[d];

  const size_t ch = (size_t)b * DI + d;
  float h[16];
  const float4* hp = (const float4*)&hstart[((size_t)c * CH + ch) * 16];
#pragma unroll
  for (int q = 0; q < 4; ++q) {
    float4 v = hp[q];
    h[q * 4] = v.x; h[q * 4 + 1] = v.y; h[q * 4 + 2] = v.z; h[q * 4 + 3] = v.w;
  }

  __syncthreads();

  const float* dtp = dt + ((size_t)b * L_SZ + t0) * DI + d;
  const ushort* xp = xc + ((size_t)b * L_SZ + t0) * DI + d;
  const ushort* rp = resb + ((size_t)b * L_SZ + t0) * DI + d;
  float* op = out + ((size_t)b * L_SZ + t0) * DI + d;

  float dtv_n = dtp[0];
  ushort xu_n = xp[0];
  ushort ru_n = rp[0];
  for (int tt = 0; tt < TC; ++tt) {
    float dtv = dtv_n;
    ushort xu = xu_n;
    ushort ru = ru_n;
    dtv_n = dtp[(size_t)(tt + 1) * DI];
    xu_n = xp[(size_t)(tt + 1) * DI];
    ru_n = rp[(size_t)(tt + 1) * DI];
    float xv = b2f(xu);
    float rv = b2f(ru);
    float dx = dtv * xv;
    const float* bp = &Bs[tt * 16];
    const float* cp = &Cs[tt * 16];
    float y0 = 0.f, y1 = 0.f, y2 = 0.f, y3 = 0.f;
#pragma unroll
    for (int s = 0; s < 16; s += 4) {
      float dA0, dA1, dA2, dA3;
      float a0 = dtv * As2[s], a1 = dtv * As2[s + 1], a2 = dtv * As2[s + 2], a3 = dtv * As2[s + 3];
      asm("v_exp_f32 %0, %1" : "=v"(dA0) : "v"(a0));
      asm("v_exp_f32 %0, %1" : "=v"(dA1) : "v"(a1));
      asm("v_exp_f32 %0, %1" : "=v"(dA2) : "v"(a2));
      asm("v_exp_f32 %0, %1" : "=v"(dA3) : "v"(a3));
      h[s]     = dA0 * h[s]     + dx * bp[s];
      h[s + 1] = dA1 * h[s + 1] + dx * bp[s + 1];
      h[s + 2] = dA2 * h[s + 2] + dx * bp[s + 2];
      h[s + 3] = dA3 * h[s + 3] + dx * bp[s + 3];
      y0 += h[s] * cp[s];
      y1 += h[s + 1] * cp[s + 1];
      y2 += h[s + 2] * cp[s + 2];
      y3 += h[s + 3] * cp[s + 3];
    }
    float y = (y0 + y1) + (y2 + y3);
    float sig = 1.f / (1.f + __expf(-rv));
    op[(size_t)tt * DI] = (y + xv * Dpv) * (rv * sig);
  }
}

// ---------------- launch ----------------

extern "C" void kernel_launch(void* const* d_in, const int* in_sizes, int n_in,
                              void* d_out, int out_size, void* d_ws, size_t ws_size,
                              hipStream_t stream) {
  const float* hs     = (const float*)d_in[0];
  const float* W_in   = (const float*)d_in[1];
  const float* conv_w = (const float*)d_in[2];
  const float* conv_b = (const float*)d_in[3];
  const float* W_x    = (const float*)d_in[4];
  const float* W_dt   = (const float*)d_in[5];
  const float* b_dt   = (const float*)d_in[6];
  const float* A_log  = (const float*)d_in[7];
  const float* D_par  = (const float*)d_in[8];
  float* out = (float*)d_out;
  char* ws = (char*)d_ws;

  // workspace layout (bytes).  Region [0, 80.2MB) = A1+Wt1+xpre is dead after
  // conv_silu and is re-used (aliased) for the scan scratch (hend/hstart/sumdt).
  size_t o = 0;
  ushort* A1   = (ushort*)(ws + o); o += (size_t)M_SZ * DM * 2;        // 25.2 MB
  ushort* Wt1  = (ushort*)(ws + o); o += (size_t)N1 * DM * 2;          // 4.7 MB
  ushort* xpre = (ushort*)(ws + o); o += (size_t)M_SZ * DI * 2;        // 50.3 MB
  ushort* resb = (ushort*)(ws + o); o += (size_t)M_SZ * DI * 2;        // 50.3 MB
  ushort* xcv  = (ushort*)(ws + o); o += (size_t)M_SZ * DI * 2;        // 50.3 MB
  float*  xdbl = (float*)(ws + o);  o += (size_t)M_SZ * 80 * 4;        // 5.2 MB
  float*  dtb  = (float*)(ws + o);  o += (size_t)M_SZ * DI * 4;        // 100.7 MB
  ushort* Wxb  = (ushort*)(ws + o); o += (size_t)80 * DI * 2;          // 0.25 MB
  ushort* Wdtp = (ushort*)(ws + o); o += (size_t)DI * 64 * 2;          // 0.2 MB
  if (ws_size < o) return;  // clean fail instead of OOB

  // scan scratch aliases the dead A1/Wt1/xpre region (52 MB < 80.2 MB)
  float* hend   = (float*)(ws + 0);
  float* hstart = (float*)(ws + (size_t)NC * CH * 16 * 4);             // +25.2 MB
  float* sumdt  = (float*)(ws + (size_t)2 * NC * CH * 16 * 4);         // +50.3 MB

  int n4 = M_SZ * DM / 4;
  cast_hidden<<<dim3((n4 + 255) / 256), dim3(256), 0, stream>>>((const float4*)hs, (ushort4*)A1, n4);
  transpose_w<<<dim3((3072 * 96 + 255) / 256), dim3(256), 0, stream>>>(W_in, Wt1);
  prep_small<<<dim3((80 * DI + DI * 64 + 255) / 256), dim3(256), 0, stream>>>(W_x, W_dt, Wxb, Wdtp);

  gemm_xz<<<dim3(M_SZ / 128, N1 / 128), dim3(256), 0, stream>>>(A1, Wt1, xpre, resb);

  conv_silu<<<dim3((M_SZ * DI) / 256), dim3(256), 0, stream>>>(xpre, conv_w, conv_b, xcv);

  xdbl_gemm<<<dim3(M_SZ / 64), dim3(256), 0, stream>>>(xcv, Wxb, xdbl);

  dt_gemm<<<dim3(M_SZ / 64), dim3(256), 0, stream>>>(xdbl, Wdtp, b_dt, dtb);

  scan_pass1<<<dim3(DI / 256, NC, B_SZ), dim3(256), 0, stream>>>(dtb, xcv, xdbl, A_log, hend, sumdt);
  scan_pass2<<<dim3(CH * 16 / 256), dim3(256), 0, stream>>>(A_log, sumdt, hend, hstart);
  scan_pass3<<<dim3(DI / 256, NC, B_SZ), dim3(256), 0, stream>>>(dtb, xcv, xdbl, resb,
                                                                 A_log, D_par, hstart, out);
}

// Round 3
// 493.088 us; speedup vs baseline: 4.6652x; 1.3093x over previous
//
#include <hip/hip_runtime.h>
#include <hip/hip_bf16.h>
#include <stdint.h>

#define B_SZ 8
#define L_SZ 2048
#define DM 768
#define DI 1536
#define DS 16
#define DR 48
#define M_SZ (B_SZ * L_SZ)   // 16384
#define N1 (2 * DI)          // 3072

#define NC 32                 // chunks per sequence
#define TC (L_SZ / NC)        // 64 steps per chunk
#define CH (B_SZ * DI)        // 12288 channels
#define KS 6                  // split-K slices for xdbl

typedef short short8 __attribute__((ext_vector_type(8)));
typedef float f32x4 __attribute__((ext_vector_type(4)));

__device__ __forceinline__ ushort f2b(float f) {
  __hip_bfloat16 h = __float2bfloat16(f);
  return *reinterpret_cast<ushort*>(&h);
}
__device__ __forceinline__ float b2f(ushort u) {
  __hip_bfloat16 h;
  *reinterpret_cast<ushort*>(&h) = u;
  return __bfloat162float(h);
}
__device__ __forceinline__ ushort f2h(float f) {
  _Float16 h = (_Float16)f;
  return *reinterpret_cast<ushort*>(&h);
}
__device__ __forceinline__ float h2f(ushort u) {
  _Float16 h;
  *reinterpret_cast<ushort*>(&h) = u;
  return (float)h;
}

__device__ __forceinline__ void gl16(const ushort* g, ushort* l) {
  __builtin_amdgcn_global_load_lds(
      (const __attribute__((address_space(1))) void*)g,
      (__attribute__((address_space(3))) void*)l, 16, 0, 0);
}

// ---------------- prep kernels ----------------

__global__ __launch_bounds__(256) void cast_hidden(const float4* __restrict__ in,
                                                   ushort4* __restrict__ out, int n4) {
  int i = blockIdx.x * 256 + threadIdx.x;
  int stride = gridDim.x * 256;
  for (; i < n4; i += stride) {
    float4 v = in[i];
    ushort4 o;
    o.x = f2b(v.x); o.y = f2b(v.y); o.z = f2b(v.z); o.w = f2b(v.w);
    out[i] = o;
  }
}

// W_in (768 x 3072) -> Wt1 bf16 (3072 x 768)
__global__ __launch_bounds__(256) void transpose_w(const float* __restrict__ w,
                                                   ushort* __restrict__ wt) {
  int idx = blockIdx.x * 256 + threadIdx.x;  // 3072 * 96
  if (idx >= 3072 * 96) return;
  int n = idx % 3072;
  int kb = (idx / 3072) * 8;
  short8 o;
#pragma unroll
  for (int j = 0; j < 8; ++j) o[j] = (short)f2b(w[(size_t)(kb + j) * 3072 + n]);
  *(short8*)(wt + (size_t)n * DM + kb) = o;
}

// casts W_x (80x1536) -> bf16 ; W_dt (1536x48) -> bf16 zero-padded to (1536x64)
__global__ __launch_bounds__(256) void prep_small(const float* __restrict__ wx_f,
                                                  const float* __restrict__ wdt_f,
                                                  ushort* __restrict__ wx_b,
                                                  ushort* __restrict__ wdt_p) {
  int idx = blockIdx.x * 256 + threadIdx.x;
  const int nwx = 80 * DI;
  const int nwdt = DI * 64;
  if (idx < nwx) {
    wx_b[idx] = f2b(wx_f[idx]);
  } else if (idx < nwx + nwdt) {
    int j = idx - nwx;
    int col = j >> 6, k = j & 63;
    wdt_p[j] = (k < DR) ? f2b(wdt_f[col * DR + k]) : (ushort)0;
  }
}

// ---------------- main GEMM: xz = A1(16384x768) @ W_in, split into x / res ----------------
// Fragment-major LDS: chunk c (= row-group mg, k-half kk) is 1 KB holding exactly one
// MFMA fragment set: lane (r,hi) <- A[mg*16+r][kk*32+hi*8 .. +7].  global_load_lds writes
// lane-linear, so per-lane global src addresses realize the layout; ds_read_b128 at
// base+lane*16 is conflict-free and uniform.

__global__ __launch_bounds__(256) void gemm_xz(const ushort* __restrict__ A,
                                               const ushort* __restrict__ Bt,
                                               ushort* __restrict__ xout,
                                               ushort* __restrict__ resout) {
  __shared__ short AsF[16 * 512];  // 16 KB
  __shared__ short BsF[16 * 512];  // 16 KB
  const int t = threadIdx.x;
  const int lane = t & 63;
  const int wid = t >> 6;
  const int wm = wid >> 1, wn = wid & 1;
  const int bm = blockIdx.x * 128;
  const int bn = blockIdx.y * 128;
  const int r = lane & 15, hi = lane >> 4;

  f32x4 acc[4][4];
#pragma unroll
  for (int m = 0; m < 4; ++m)
#pragma unroll
    for (int n = 0; n < 4; ++n) acc[m][n] = f32x4{0.f, 0.f, 0.f, 0.f};

  const ushort* gA[4];
  const ushort* gB[4];
#pragma unroll
  for (int i = 0; i < 4; ++i) {
    int c = wid * 4 + i;
    int mg = c >> 1, kk = c & 1;
    gA[i] = A + (size_t)(bm + mg * 16 + r) * DM + kk * 32 + hi * 8;
    gB[i] = Bt + (size_t)(bn + mg * 16 + r) * DM + kk * 32 + hi * 8;
  }

  for (int k0 = 0; k0 < DM; k0 += 64) {
#pragma unroll
    for (int i = 0; i < 4; ++i) {
      int c = wid * 4 + i;
      gl16(gA[i] + k0, (ushort*)&AsF[c * 512]);
      gl16(gB[i] + k0, (ushort*)&BsF[c * 512]);
    }
    __syncthreads();  // drains vmcnt(0) -> LDS valid
#pragma unroll
    for (int kk = 0; kk < 2; ++kk) {
      short8 af[4], bfr[4];
#pragma unroll
      for (int m = 0; m < 4; ++m)
        af[m] = *(const short8*)&AsF[(((wm * 4 + m) << 1) + kk) * 512 + lane * 8];
#pragma unroll
      for (int n = 0; n < 4; ++n)
        bfr[n] = *(const short8*)&BsF[(((wn * 4 + n) << 1) + kk) * 512 + lane * 8];
#pragma unroll
      for (int m = 0; m < 4; ++m)
#pragma unroll
        for (int n = 0; n < 4; ++n)
          acc[m][n] = __builtin_amdgcn_mfma_f32_16x16x32_bf16(af[m], bfr[n], acc[m][n], 0, 0, 0);
    }
    __syncthreads();  // all reads done before next-stage overwrite
  }

  const bool isx = (bn < DI);
  ushort* outp = isx ? xout : resout;
  const int cbase = bn - (isx ? 0 : DI) + wn * 64;
#pragma unroll
  for (int m = 0; m < 4; ++m)
#pragma unroll
    for (int n = 0; n < 4; ++n) {
      int col = cbase + n * 16 + r;
#pragma unroll
      for (int j = 0; j < 4; ++j) {
        int row = bm + wm * 64 + m * 16 + hi * 4 + j;
        outp[(size_t)row * DI + col] = f2b(acc[m][n][j]);
      }
    }
}

// ---------------- depthwise causal conv (K=4) + SiLU, 8-wide ----------------

__global__ __launch_bounds__(256) void conv_silu(const ushort* __restrict__ xp,
                                                 const float* __restrict__ cw,
                                                 const float* __restrict__ cb,
                                                 ushort* __restrict__ xc) {
  int tid = blockIdx.x * 256 + threadIdx.x;  // < M_SZ*DI/8
  const int nd = DI / 8;                     // 192
  int db = tid % nd;
  int row = tid / nd;
  int d0 = db * 8;
  int l = row & (L_SZ - 1);
  const ushort* base = xp + (size_t)row * DI + d0;
  short8 z8 = {0, 0, 0, 0, 0, 0, 0, 0};
  short8 x0 = *(const short8*)base;
  short8 xm1 = (l >= 1) ? *(const short8*)(base - DI) : z8;
  short8 xm2 = (l >= 2) ? *(const short8*)(base - 2 * DI) : z8;
  short8 xm3 = (l >= 3) ? *(const short8*)(base - 3 * DI) : z8;
  short8 o;
#pragma unroll
  for (int j = 0; j < 8; ++j) {
    float4 w = *(const float4*)(cw + (size_t)(d0 + j) * 4);
    float a = cb[d0 + j] + w.x * b2f((ushort)xm3[j]) + w.y * b2f((ushort)xm2[j]) +
              w.z * b2f((ushort)xm1[j]) + w.w * b2f((ushort)x0[j]);
    float s = a / (1.f + __expf(-a));
    o[j] = (short)f2b(s);
  }
  *(short8*)(xc + (size_t)row * DI + d0) = o;
}

// ---------------- x_dbl: split-K partials  xdp[ks][16384][80] fp32 ----------------

__global__ __launch_bounds__(256) void xdbl_gemm(const ushort* __restrict__ xc,
                                                 const ushort* __restrict__ wx,
                                                 float* __restrict__ xdp) {
  int wave = blockIdx.x * 4 + (threadIdx.x >> 6);
  int ks = blockIdx.y;
  int lane = threadIdx.x & 63;
  int r = lane & 15, hi = lane >> 4;
  int row0 = wave * 16;
  f32x4 acc[5];
#pragma unroll
  for (int n = 0; n < 5; ++n) acc[n] = f32x4{0.f, 0.f, 0.f, 0.f};
  const int kbeg = ks * (DI / KS), kend = kbeg + DI / KS;
  for (int k0 = kbeg; k0 < kend; k0 += 32) {
    short8 a = *(const short8*)(xc + (size_t)(row0 + r) * DI + k0 + hi * 8);
#pragma unroll
    for (int n = 0; n < 5; ++n) {
      short8 b = *(const short8*)(wx + (size_t)(n * 16 + r) * DI + k0 + hi * 8);
      acc[n] = __builtin_amdgcn_mfma_f32_16x16x32_bf16(a, b, acc[n], 0, 0, 0);
    }
  }
  float* op = xdp + (size_t)ks * M_SZ * 80;
#pragma unroll
  for (int n = 0; n < 5; ++n)
#pragma unroll
    for (int j = 0; j < 4; ++j)
      op[(size_t)(row0 + hi * 4 + j) * 80 + n * 16 + r] = acc[n][j];
}

__global__ __launch_bounds__(256) void reduce_xd(const float4* __restrict__ xdp,
                                                 float4* __restrict__ xd) {
  int i = blockIdx.x * 256 + threadIdx.x;  // over 16384*80/4 = 327680
  if (i >= M_SZ * 20) return;
  float4 s = xdp[i];
#pragma unroll
  for (int k = 1; k < KS; ++k) {
    float4 v = xdp[(size_t)k * M_SZ * 20 + i];
    s.x += v.x; s.y += v.y; s.z += v.z; s.w += v.w;
  }
  xd[i] = s;
}

// ---------------- dt = softplus(x_dbl[:, :48] @ W_dt^T + b_dt) -> fp16 ----------------

__device__ __forceinline__ short8 pack8f(const float* p) {
  short8 v;
#pragma unroll
  for (int i = 0; i < 8; ++i) v[i] = (short)f2b(p[i]);
  return v;
}

__global__ __launch_bounds__(256) void dt_gemm(const float* __restrict__ xd,
                                               const ushort* __restrict__ wdtp,
                                               const float* __restrict__ bdt,
                                               ushort* __restrict__ dt) {
  int wave = blockIdx.x * 4 + (threadIdx.x >> 6);
  int lane = threadIdx.x & 63;
  int r = lane & 15, hi = lane >> 4;
  int row0 = wave * 16;
  int c0 = blockIdx.y * 64;

  float atmp[8];
  const float* ap = xd + (size_t)(row0 + r) * 80 + hi * 8;
  float4 q0 = *(const float4*)ap, q1 = *(const float4*)(ap + 4);
  atmp[0] = q0.x; atmp[1] = q0.y; atmp[2] = q0.z; atmp[3] = q0.w;
  atmp[4] = q1.x; atmp[5] = q1.y; atmp[6] = q1.z; atmp[7] = q1.w;
  short8 a0 = pack8f(atmp);
  short8 a1 = {0, 0, 0, 0, 0, 0, 0, 0};
  if (hi < 2) {
    const float* ap1 = xd + (size_t)(row0 + r) * 80 + 32 + hi * 8;
    float4 p0 = *(const float4*)ap1, p1 = *(const float4*)(ap1 + 4);
    atmp[0] = p0.x; atmp[1] = p0.y; atmp[2] = p0.z; atmp[3] = p0.w;
    atmp[4] = p1.x; atmp[5] = p1.y; atmp[6] = p1.z; atmp[7] = p1.w;
    a1 = pack8f(atmp);
  }

  f32x4 acc[4];
#pragma unroll
  for (int n = 0; n < 4; ++n) acc[n] = f32x4{0.f, 0.f, 0.f, 0.f};
#pragma unroll
  for (int n = 0; n < 4; ++n) {
    const ushort* wp = wdtp + (size_t)(c0 + n * 16 + r) * 64;
    short8 b0 = *(const short8*)(wp + hi * 8);
    short8 b1 = *(const short8*)(wp + 32 + hi * 8);
    acc[n] = __builtin_amdgcn_mfma_f32_16x16x32_bf16(a0, b0, acc[n], 0, 0, 0);
    acc[n] = __builtin_amdgcn_mfma_f32_16x16x32_bf16(a1, b1, acc[n], 0, 0, 0);
  }
#pragma unroll
  for (int n = 0; n < 4; ++n)
#pragma unroll
    for (int j = 0; j < 4; ++j) {
      int col = c0 + n * 16 + r;
      float z = acc[n][j] + bdt[col];
      float sp = (z > 20.f) ? z : __logf(1.f + __expf(z));
      dt[(size_t)(row0 + hi * 4 + j) * DI + col] = f2h(sp);
    }
}

// ---------------- chunked selective scan ----------------

__global__ __launch_bounds__(256) void scan_pass1(const ushort* __restrict__ dt,
                                                  const ushort* __restrict__ xc,
                                                  const float* __restrict__ xd,
                                                  const float* __restrict__ A_log,
                                                  float* __restrict__ hend,
                                                  float* __restrict__ sumdt) {
  const int d = blockIdx.x * 256 + threadIdx.x;
  const int c = blockIdx.y, b = blockIdx.z;
  const int t0 = c * TC;

  __shared__ float Bs[TC * 16];  // 4 KB
  for (int i = threadIdx.x; i < TC * 16; i += 256) {
    int tt = i >> 4, s = i & 15;
    Bs[i] = xd[((size_t)(b * L_SZ + t0 + tt)) * 80 + DR + s];
  }

  float As2[16];
#pragma unroll
  for (int s = 0; s < 16; ++s)
    As2[s] = -__expf(A_log[d * DS + s]) * 1.44269504088896f;  // A * log2(e)

  __syncthreads();

  float h[16];
#pragma unroll
  for (int s = 0; s < 16; ++s) h[s] = 0.f;
  float sd = 0.f;

  const ushort* dtp = dt + ((size_t)b * L_SZ + t0) * DI + d;
  const ushort* xp = xc + ((size_t)b * L_SZ + t0) * DI + d;

  ushort dtu_n = dtp[0];
  ushort xu_n = xp[0];
  for (int tt = 0; tt < TC; ++tt) {
    ushort dtu = dtu_n;
    ushort xu = xu_n;
    dtu_n = dtp[(size_t)(tt + 1) * DI];
    xu_n = xp[(size_t)(tt + 1) * DI];
    float dtv = h2f(dtu);
    float xv = b2f(xu);
    sd += dtv;
    float dx = dtv * xv;
    const float* bp = &Bs[tt * 16];
#pragma unroll
    for (int s = 0; s < 16; ++s) {
      float arg = dtv * As2[s];
      float dA;
      asm("v_exp_f32 %0, %1" : "=v"(dA) : "v"(arg));
      h[s] = dA * h[s] + dx * bp[s];
    }
  }

  const size_t ch = (size_t)b * DI + d;
  sumdt[ch * NC + c] = sd;
  float4* hp = (float4*)&hend[((size_t)c * CH + ch) * 16];
#pragma unroll
  for (int q = 0; q < 4; ++q)
    hp[q] = make_float4(h[q * 4], h[q * 4 + 1], h[q * 4 + 2], h[q * 4 + 3]);
}

__global__ __launch_bounds__(256) void scan_pass2(const float* __restrict__ A_log,
                                                  const float* __restrict__ sumdt,
                                                  const float* __restrict__ hend,
                                                  float* __restrict__ hstart) {
  int idx = blockIdx.x * 256 + threadIdx.x;  // ch*16 + s
  int ch = idx >> 4, s = idx & 15;
  int d = ch % DI;
  float A = -__expf(A_log[d * DS + s]);
  float h = 0.f;
  for (int c = 0; c < NC; ++c) {
    hstart[((size_t)c * CH + ch) * 16 + s] = h;
    float sd = sumdt[(size_t)ch * NC + c];
    h = __expf(A * sd) * h + hend[((size_t)c * CH + ch) * 16 + s];
  }
}

__global__ __launch_bounds__(256) void scan_pass3(const ushort* __restrict__ dt,
                                                  const ushort* __restrict__ xc,
                                                  const float* __restrict__ xd,
                                                  const ushort* __restrict__ resb,
                                                  const float* __restrict__ A_log,
                                                  const float* __restrict__ Dp,
                                                  const float* __restrict__ hstart,
                                                  float* __restrict__ out) {
  const int d = blockIdx.x * 256 + threadIdx.x;
  const int c = blockIdx.y, b = blockIdx.z;
  const int t0 = c * TC;

  __shared__ float Bs[TC * 16];  // 4 KB
  __shared__ float Cs[TC * 16];  // 4 KB
  for (int i = threadIdx.x; i < TC * 16; i += 256) {
    int tt = i >> 4, s = i & 15;
    size_t row = ((size_t)(b * L_SZ + t0 + tt)) * 80;
    Bs[i] = xd[row + DR + s];
    Cs[i] = xd[row + DR + DS + s];
  }

  float As2[16];
#pragma unroll
  for (int s = 0; s < 16; ++s)
    As2[s] = -__expf(A_log[d * DS + s]) * 1.44269504088896f;
  const float Dpv = Dp[d];

  const size_t ch = (size_t)b * DI + d;
  float h[16];
  const float4* hp = (const float4*)&hstart[((size_t)c * CH + ch) * 16];
#pragma unroll
  for (int q = 0; q < 4; ++q) {
    float4 v = hp[q];
    h[q * 4] = v.x; h[q * 4 + 1] = v.y; h[q * 4 + 2] = v.z; h[q * 4 + 3] = v.w;
  }

  __syncthreads();

  const ushort* dtp = dt + ((size_t)b * L_SZ + t0) * DI + d;
  const ushort* xp = xc + ((size_t)b * L_SZ + t0) * DI + d;
  const ushort* rp = resb + ((size_t)b * L_SZ + t0) * DI + d;
  float* op = out + ((size_t)b * L_SZ + t0) * DI + d;

  ushort dtu_n = dtp[0];
  ushort xu_n = xp[0];
  ushort ru_n = rp[0];
  for (int tt = 0; tt < TC; ++tt) {
    ushort dtu = dtu_n;
    ushort xu = xu_n;
    ushort ru = ru_n;
    dtu_n = dtp[(size_t)(tt + 1) * DI];
    xu_n = xp[(size_t)(tt + 1) * DI];
    ru_n = rp[(size_t)(tt + 1) * DI];
    float dtv = h2f(dtu);
    float xv = b2f(xu);
    float rv = b2f(ru);
    float dx = dtv * xv;
    const float* bp = &Bs[tt * 16];
    const float* cp = &Cs[tt * 16];
    float y0 = 0.f, y1 = 0.f, y2 = 0.f, y3 = 0.f;
#pragma unroll
    for (int s = 0; s < 16; s += 4) {
      float dA0, dA1, dA2, dA3;
      float a0 = dtv * As2[s], a1 = dtv * As2[s + 1], a2 = dtv * As2[s + 2], a3 = dtv * As2[s + 3];
      asm("v_exp_f32 %0, %1" : "=v"(dA0) : "v"(a0));
      asm("v_exp_f32 %0, %1" : "=v"(dA1) : "v"(a1));
      asm("v_exp_f32 %0, %1" : "=v"(dA2) : "v"(a2));
      asm("v_exp_f32 %0, %1" : "=v"(dA3) : "v"(a3));
      h[s]     = dA0 * h[s]     + dx * bp[s];
      h[s + 1] = dA1 * h[s + 1] + dx * bp[s + 1];
      h[s + 2] = dA2 * h[s + 2] + dx * bp[s + 2];
      h[s + 3] = dA3 * h[s + 3] + dx * bp[s + 3];
      y0 += h[s] * cp[s];
      y1 += h[s + 1] * cp[s + 1];
      y2 += h[s + 2] * cp[s + 2];
      y3 += h[s + 3] * cp[s + 3];
    }
    float y = (y0 + y1) + (y2 + y3);
    float sig = 1.f / (1.f + __expf(-rv));
    op[(size_t)tt * DI] = (y + xv * Dpv) * (rv * sig);
  }
}

// ---------------- launch ----------------

extern "C" void kernel_launch(void* const* d_in, const int* in_sizes, int n_in,
                              void* d_out, int out_size, void* d_ws, size_t ws_size,
                              hipStream_t stream) {
  const float* hs     = (const float*)d_in[0];
  const float* W_in   = (const float*)d_in[1];
  const float* conv_w = (const float*)d_in[2];
  const float* conv_b = (const float*)d_in[3];
  const float* W_x    = (const float*)d_in[4];
  const float* W_dt   = (const float*)d_in[5];
  const float* b_dt   = (const float*)d_in[6];
  const float* A_log  = (const float*)d_in[7];
  const float* D_par  = (const float*)d_in[8];
  float* out = (float*)d_out;
  char* ws = (char*)d_ws;

  // workspace layout (bytes).  Region [0, 80.2MB) = A1+Wt1+xpre is dead after
  // conv_silu and is re-used (aliased) for the scan scratch (hend/hstart/sumdt).
  size_t o = 0;
  ushort* A1   = (ushort*)(ws + o); o += (size_t)M_SZ * DM * 2;        // 25.2 MB
  ushort* Wt1  = (ushort*)(ws + o); o += (size_t)N1 * DM * 2;          // 4.7 MB
  ushort* xpre = (ushort*)(ws + o); o += (size_t)M_SZ * DI * 2;        // 50.3 MB
  ushort* resb = (ushort*)(ws + o); o += (size_t)M_SZ * DI * 2;        // 50.3 MB
  ushort* xcv  = (ushort*)(ws + o); o += (size_t)M_SZ * DI * 2;        // 50.3 MB
  float*  xdbl = (float*)(ws + o);  o += (size_t)M_SZ * 80 * 4;        // 5.2 MB
  ushort* dtb  = (ushort*)(ws + o); o += (size_t)M_SZ * DI * 2;        // 50.3 MB (fp16)
  float*  xdp  = (float*)(ws + o);  o += (size_t)KS * M_SZ * 80 * 4;   // 31.5 MB
  ushort* Wxb  = (ushort*)(ws + o); o += (size_t)80 * DI * 2;          // 0.25 MB
  ushort* Wdtp = (ushort*)(ws + o); o += (size_t)DI * 64 * 2;          // 0.2 MB
  if (ws_size < o) return;  // clean fail instead of OOB

  // scan scratch aliases the dead A1/Wt1/xpre region (52 MB < 80.2 MB)
  float* hend   = (float*)(ws + 0);
  float* hstart = (float*)(ws + (size_t)NC * CH * 16 * 4);             // +25.2 MB
  float* sumdt  = (float*)(ws + (size_t)2 * NC * CH * 16 * 4);         // +50.3 MB

  int n4 = M_SZ * DM / 4;
  cast_hidden<<<dim3((n4 + 255) / 256), dim3(256), 0, stream>>>((const float4*)hs, (ushort4*)A1, n4);
  transpose_w<<<dim3((3072 * 96 + 255) / 256), dim3(256), 0, stream>>>(W_in, Wt1);
  prep_small<<<dim3((80 * DI + DI * 64 + 255) / 256), dim3(256), 0, stream>>>(W_x, W_dt, Wxb, Wdtp);

  gemm_xz<<<dim3(M_SZ / 128, N1 / 128), dim3(256), 0, stream>>>(A1, Wt1, xpre, resb);

  conv_silu<<<dim3(M_SZ * DI / 8 / 256), dim3(256), 0, stream>>>(xpre, conv_w, conv_b, xcv);

  xdbl_gemm<<<dim3(M_SZ / 64, KS), dim3(256), 0, stream>>>(xcv, Wxb, xdp);
  reduce_xd<<<dim3((M_SZ * 20 + 255) / 256), dim3(256), 0, stream>>>((const float4*)xdp, (float4*)xdbl);

  dt_gemm<<<dim3(M_SZ / 64, 24), dim3(256), 0, stream>>>(xdbl, Wdtp, b_dt, dtb);

  scan_pass1<<<dim3(DI / 256, NC, B_SZ), dim3(256), 0, stream>>>(dtb, xcv, xdbl, A_log, hend, sumdt);
  scan_pass2<<<dim3(CH * 16 / 256), dim3(256), 0, stream>>>(A_log, sumdt, hend, hstart);
  scan_pass3<<<dim3(DI / 256, NC, B_SZ), dim3(256), 0, stream>>>(dtb, xcv, xdbl, resb,
                                                                 A_log, D_par, hstart, out);
}

// Round 4
// 452.339 us; speedup vs baseline: 5.0855x; 1.0901x over previous
//
#include <hip/hip_runtime.h>
#include <hip/hip_bf16.h>
#include <stdint.h>

#define B_SZ 8
#define L_SZ 2048
#define DM 768
#define DI 1536
#define DS 16
#define DR 48
#define M_SZ (B_SZ * L_SZ)   // 16384
#define N1 (2 * DI)          // 3072

#define NC 32                 // chunks per sequence
#define TC (L_SZ / NC)        // 64 steps per chunk
#define CH (B_SZ * DI)        // 12288 channels
#define KS 6                  // split-K slices for xdbl
#define NT (DM / 64)          // 12 K-tiles for gemm_xz

typedef short short8 __attribute__((ext_vector_type(8)));
typedef float f32x4 __attribute__((ext_vector_type(4)));

__device__ __forceinline__ ushort f2b(float f) {
  __hip_bfloat16 h = __float2bfloat16(f);
  return *reinterpret_cast<ushort*>(&h);
}
__device__ __forceinline__ float b2f(ushort u) {
  __hip_bfloat16 h;
  *reinterpret_cast<ushort*>(&h) = u;
  return __bfloat162float(h);
}
__device__ __forceinline__ ushort f2h(float f) {
  _Float16 h = (_Float16)f;
  return *reinterpret_cast<ushort*>(&h);
}
__device__ __forceinline__ float h2f(ushort u) {
  _Float16 h;
  *reinterpret_cast<ushort*>(&h) = u;
  return (float)h;
}

__device__ __forceinline__ void gl16(const ushort* g, ushort* l) {
  __builtin_amdgcn_global_load_lds(
      (const __attribute__((address_space(1))) void*)g,
      (__attribute__((address_space(3))) void*)l, 16, 0, 0);
}

// ---------------- prep kernels ----------------

__global__ __launch_bounds__(256) void cast_hidden(const float4* __restrict__ in,
                                                   ushort4* __restrict__ out, int n4) {
  int i = blockIdx.x * 256 + threadIdx.x;
  int stride = gridDim.x * 256;
  for (; i < n4; i += stride) {
    float4 v = in[i];
    ushort4 o;
    o.x = f2b(v.x); o.y = f2b(v.y); o.z = f2b(v.z); o.w = f2b(v.w);
    out[i] = o;
  }
}

// W_in (768 x 3072) -> Wt1 bf16 (3072 x 768)
__global__ __launch_bounds__(256) void transpose_w(const float* __restrict__ w,
                                                   ushort* __restrict__ wt) {
  int idx = blockIdx.x * 256 + threadIdx.x;  // 3072 * 96
  if (idx >= 3072 * 96) return;
  int n = idx % 3072;
  int kb = (idx / 3072) * 8;
  short8 o;
#pragma unroll
  for (int j = 0; j < 8; ++j) o[j] = (short)f2b(w[(size_t)(kb + j) * 3072 + n]);
  *(short8*)(wt + (size_t)n * DM + kb) = o;
}

// casts W_x (80x1536) -> bf16 ; W_dt (1536x48) -> bf16 zero-padded to (1536x64)
__global__ __launch_bounds__(256) void prep_small(const float* __restrict__ wx_f,
                                                  const float* __restrict__ wdt_f,
                                                  ushort* __restrict__ wx_b,
                                                  ushort* __restrict__ wdt_p) {
  int idx = blockIdx.x * 256 + threadIdx.x;
  const int nwx = 80 * DI;
  const int nwdt = DI * 64;
  if (idx < nwx) {
    wx_b[idx] = f2b(wx_f[idx]);
  } else if (idx < nwx + nwdt) {
    int j = idx - nwx;
    int col = j >> 6, k = j & 63;
    wdt_p[j] = (k < DR) ? f2b(wdt_f[col * DR + k]) : (ushort)0;
  }
}

// ---------------- main GEMM: xz = A1(16384x768) @ W_in  (256x256 tile, 8-phase) -----------
// Fragment-major LDS: chunk c = mg*2+kk is 1 KB = one MFMA fragment set
// (lane (r,hi) <- M[mg*16+r][kk*32+hi*8..+7]); gl16 writes lane-linear, ds_read_b128 at
// base+lane*16 is conflict-free.  Double-buffered K-tiles, raw s_barrier (no vmcnt drain),
// vmcnt(0) once per K-tile after the 4th MFMA cluster, setprio around MFMA.

__global__ __launch_bounds__(512, 1) void gemm_xz(const ushort* __restrict__ A,
                                                  const ushort* __restrict__ Bt,
                                                  ushort* __restrict__ xout,
                                                  ushort* __restrict__ resout) {
  __shared__ ushort lds[65536];  // 128 KiB: [db(2)][A/B(2)][chunk(32)][512]

  const int t = threadIdx.x;
  const int lane = t & 63;
  const int wid = t >> 6;
  const int wm = wid >> 2, wn = wid & 3;
  const int r = lane & 15, hi = lane >> 4;

  // XCD-aware bijective swizzle (768 % 8 == 0)
  const int g = blockIdx.x;
  const int swz = (g & 7) * (768 / 8) + (g >> 3);
  const int bx = swz & 63;        // 64 M-blocks
  const int by = swz >> 6;        // 12 N-blocks
  const int bm = bx * 256;
  const int bn = by * 256;

  // this wave's 8 staging chunks (waves 0-3: A chunks 0..31; waves 4-7: B chunks 0..31)
  const bool isA = wid < 4;
  const int w4 = wid & 3;
  const ushort* gsrc[8];
  int ldso[8];  // LDS short-offset within a db buffer
#pragma unroll
  for (int i = 0; i < 8; ++i) {
    int c = w4 * 8 + i;
    int mg = c >> 1, kkc = c & 1;
    gsrc[i] = (isA ? A + (size_t)(bm + mg * 16 + r) * DM
                   : Bt + (size_t)(bn + mg * 16 + r) * DM) + kkc * 32 + hi * 8;
    ldso[i] = (isA ? 0 : 16384) + c * 512;
  }

  f32x4 acc[8][4];
#pragma unroll
  for (int m = 0; m < 8; ++m)
#pragma unroll
    for (int n = 0; n < 4; ++n) acc[m][n] = f32x4{0.f, 0.f, 0.f, 0.f};

  // prologue: stage K-tile 0 into db0
#pragma unroll
  for (int i = 0; i < 8; ++i) gl16(gsrc[i], &lds[ldso[i]]);
  asm volatile("s_waitcnt vmcnt(0)" ::: "memory");
  __builtin_amdgcn_s_barrier();

  for (int kt = 0; kt < NT; ++kt) {
    const int cur = kt & 1;
    const ushort* bufA = &lds[cur * 32768];
    const ushort* bufB = bufA + 16384;
    ushort* nxt = &lds[(cur ^ 1) * 32768];
    const int koff = (kt + 1) * 64;
    const bool more = (kt + 1 < NT);

    short8 afr[4][2], bfr[2][2];
#pragma unroll
    for (int q = 0; q < 4; ++q) {
      const int mq = q >> 1, nq = q & 1;
      if (nq == 0) {
#pragma unroll
        for (int m = 0; m < 4; ++m)
#pragma unroll
          for (int kk = 0; kk < 2; ++kk)
            afr[m][kk] = *(const short8*)&bufA[((wm * 8 + mq * 4 + m) * 2 + kk) * 512 + lane * 8];
      }
#pragma unroll
      for (int n = 0; n < 2; ++n)
#pragma unroll
        for (int kk = 0; kk < 2; ++kk)
          bfr[n][kk] = *(const short8*)&bufB[((wn * 4 + nq * 2 + n) * 2 + kk) * 512 + lane * 8];

      if (more) {
        gl16(gsrc[2 * q] + koff, nxt + ldso[2 * q]);
        gl16(gsrc[2 * q + 1] + koff, nxt + ldso[2 * q + 1]);
      }

      asm volatile("s_barrier" ::: "memory");

      __builtin_amdgcn_s_setprio(1);
#pragma unroll
      for (int m = 0; m < 4; ++m)
#pragma unroll
        for (int n = 0; n < 2; ++n) {
          f32x4 a = acc[mq * 4 + m][nq * 2 + n];
          a = __builtin_amdgcn_mfma_f32_16x16x32_bf16(afr[m][0], bfr[n][0], a, 0, 0, 0);
          a = __builtin_amdgcn_mfma_f32_16x16x32_bf16(afr[m][1], bfr[n][1], a, 0, 0, 0);
          acc[mq * 4 + m][nq * 2 + n] = a;
        }
      __builtin_amdgcn_s_setprio(0);

      if (q == 3) asm volatile("s_waitcnt vmcnt(0)" ::: "memory");
      asm volatile("s_barrier" ::: "memory");
    }
  }

  const bool isx = (bn < DI);
  ushort* outp = isx ? xout : resout;
  const int cbase = bn - (isx ? 0 : DI) + wn * 64;
#pragma unroll
  for (int mf = 0; mf < 8; ++mf)
#pragma unroll
    for (int nf = 0; nf < 4; ++nf) {
      int col = cbase + nf * 16 + r;
#pragma unroll
      for (int j = 0; j < 4; ++j) {
        int row = bm + wm * 128 + mf * 16 + hi * 4 + j;
        outp[(size_t)row * DI + col] = f2b(acc[mf][nf][j]);
      }
    }
}

// ---------------- depthwise causal conv (K=4) + SiLU, 8-wide ----------------

__global__ __launch_bounds__(256) void conv_silu(const ushort* __restrict__ xp,
                                                 const float* __restrict__ cw,
                                                 const float* __restrict__ cb,
                                                 ushort* __restrict__ xc) {
  int tid = blockIdx.x * 256 + threadIdx.x;  // < M_SZ*DI/8
  const int nd = DI / 8;                     // 192
  int db = tid % nd;
  int row = tid / nd;
  int d0 = db * 8;
  int l = row & (L_SZ - 1);
  const ushort* base = xp + (size_t)row * DI + d0;
  short8 z8 = {0, 0, 0, 0, 0, 0, 0, 0};
  short8 x0 = *(const short8*)base;
  short8 xm1 = (l >= 1) ? *(const short8*)(base - DI) : z8;
  short8 xm2 = (l >= 2) ? *(const short8*)(base - 2 * DI) : z8;
  short8 xm3 = (l >= 3) ? *(const short8*)(base - 3 * DI) : z8;
  short8 o;
#pragma unroll
  for (int j = 0; j < 8; ++j) {
    float4 w = *(const float4*)(cw + (size_t)(d0 + j) * 4);
    float a = cb[d0 + j] + w.x * b2f((ushort)xm3[j]) + w.y * b2f((ushort)xm2[j]) +
              w.z * b2f((ushort)xm1[j]) + w.w * b2f((ushort)x0[j]);
    float s = a / (1.f + __expf(-a));
    o[j] = (short)f2b(s);
  }
  *(short8*)(xc + (size_t)row * DI + d0) = o;
}

// ---------------- x_dbl: split-K partials  xdp[ks][16384][80] fp32 ----------------

__global__ __launch_bounds__(256) void xdbl_gemm(const ushort* __restrict__ xc,
                                                 const ushort* __restrict__ wx,
                                                 float* __restrict__ xdp) {
  int wave = blockIdx.x * 4 + (threadIdx.x >> 6);
  int ks = blockIdx.y;
  int lane = threadIdx.x & 63;
  int r = lane & 15, hi = lane >> 4;
  int row0 = wave * 16;
  f32x4 acc[5];
#pragma unroll
  for (int n = 0; n < 5; ++n) acc[n] = f32x4{0.f, 0.f, 0.f, 0.f};
  const int kbeg = ks * (DI / KS), kend = kbeg + DI / KS;
  for (int k0 = kbeg; k0 < kend; k0 += 32) {
    short8 a = *(const short8*)(xc + (size_t)(row0 + r) * DI + k0 + hi * 8);
#pragma unroll
    for (int n = 0; n < 5; ++n) {
      short8 b = *(const short8*)(wx + (size_t)(n * 16 + r) * DI + k0 + hi * 8);
      acc[n] = __builtin_amdgcn_mfma_f32_16x16x32_bf16(a, b, acc[n], 0, 0, 0);
    }
  }
  float* op = xdp + (size_t)ks * M_SZ * 80;
#pragma unroll
  for (int n = 0; n < 5; ++n)
#pragma unroll
    for (int j = 0; j < 4; ++j)
      op[(size_t)(row0 + hi * 4 + j) * 80 + n * 16 + r] = acc[n][j];
}

__global__ __launch_bounds__(256) void reduce_xd(const float4* __restrict__ xdp,
                                                 float4* __restrict__ xd) {
  int i = blockIdx.x * 256 + threadIdx.x;  // over 16384*80/4 = 327680
  if (i >= M_SZ * 20) return;
  float4 s = xdp[i];
#pragma unroll
  for (int k = 1; k < KS; ++k) {
    float4 v = xdp[(size_t)k * M_SZ * 20 + i];
    s.x += v.x; s.y += v.y; s.z += v.z; s.w += v.w;
  }
  xd[i] = s;
}

// ---------------- dt = softplus(x_dbl[:, :48] @ W_dt^T + b_dt) -> fp16 ----------------

__device__ __forceinline__ short8 pack8f(const float* p) {
  short8 v;
#pragma unroll
  for (int i = 0; i < 8; ++i) v[i] = (short)f2b(p[i]);
  return v;
}

__global__ __launch_bounds__(256) void dt_gemm(const float* __restrict__ xd,
                                               const ushort* __restrict__ wdtp,
                                               const float* __restrict__ bdt,
                                               ushort* __restrict__ dt) {
  int wave = blockIdx.x * 4 + (threadIdx.x >> 6);
  int lane = threadIdx.x & 63;
  int r = lane & 15, hi = lane >> 4;
  int row0 = wave * 16;
  int c0 = blockIdx.y * 64;

  float atmp[8];
  const float* ap = xd + (size_t)(row0 + r) * 80 + hi * 8;
  float4 q0 = *(const float4*)ap, q1 = *(const float4*)(ap + 4);
  atmp[0] = q0.x; atmp[1] = q0.y; atmp[2] = q0.z; atmp[3] = q0.w;
  atmp[4] = q1.x; atmp[5] = q1.y; atmp[6] = q1.z; atmp[7] = q1.w;
  short8 a0 = pack8f(atmp);
  short8 a1 = {0, 0, 0, 0, 0, 0, 0, 0};
  if (hi < 2) {
    const float* ap1 = xd + (size_t)(row0 + r) * 80 + 32 + hi * 8;
    float4 p0 = *(const float4*)ap1, p1 = *(const float4*)(ap1 + 4);
    atmp[0] = p0.x; atmp[1] = p0.y; atmp[2] = p0.z; atmp[3] = p0.w;
    atmp[4] = p1.x; atmp[5] = p1.y; atmp[6] = p1.z; atmp[7] = p1.w;
    a1 = pack8f(atmp);
  }

  f32x4 acc[4];
#pragma unroll
  for (int n = 0; n < 4; ++n) acc[n] = f32x4{0.f, 0.f, 0.f, 0.f};
#pragma unroll
  for (int n = 0; n < 4; ++n) {
    const ushort* wp = wdtp + (size_t)(c0 + n * 16 + r) * 64;
    short8 b0 = *(const short8*)(wp + hi * 8);
    short8 b1 = *(const short8*)(wp + 32 + hi * 8);
    acc[n] = __builtin_amdgcn_mfma_f32_16x16x32_bf16(a0, b0, acc[n], 0, 0, 0);
    acc[n] = __builtin_amdgcn_mfma_f32_16x16x32_bf16(a1, b1, acc[n], 0, 0, 0);
  }
#pragma unroll
  for (int n = 0; n < 4; ++n)
#pragma unroll
    for (int j = 0; j < 4; ++j) {
      int col = c0 + n * 16 + r;
      float z = acc[n][j] + bdt[col];
      float sp = (z > 20.f) ? z : __logf(1.f + __expf(z));
      dt[(size_t)(row0 + hi * 4 + j) * DI + col] = f2h(sp);
    }
}

// ---------------- chunked selective scan ----------------

__global__ __launch_bounds__(256) void scan_pass1(const ushort* __restrict__ dt,
                                                  const ushort* __restrict__ xc,
                                                  const float* __restrict__ xd,
                                                  const float* __restrict__ A_log,
                                                  float* __restrict__ hend,
                                                  float* __restrict__ sumdt) {
  const int d = blockIdx.x * 256 + threadIdx.x;
  const int c = blockIdx.y, b = blockIdx.z;
  const int t0 = c * TC;

  __shared__ float Bs[TC * 16];  // 4 KB
  for (int i = threadIdx.x; i < TC * 16; i += 256) {
    int tt = i >> 4, s = i & 15;
    Bs[i] = xd[((size_t)(b * L_SZ + t0 + tt)) * 80 + DR + s];
  }

  float As2[16];
#pragma unroll
  for (int s = 0; s < 16; ++s)
    As2[s] = -__expf(A_log[d * DS + s]) * 1.44269504088896f;  // A * log2(e)

  __syncthreads();

  float h[16];
#pragma unroll
  for (int s = 0; s < 16; ++s) h[s] = 0.f;
  float sd = 0.f;

  const ushort* dtp = dt + ((size_t)b * L_SZ + t0) * DI + d;
  const ushort* xp = xc + ((size_t)b * L_SZ + t0) * DI + d;

  ushort dtu_n = dtp[0];
  ushort xu_n = xp[0];
  for (int tt = 0; tt < TC; ++tt) {
    ushort dtu = dtu_n;
    ushort xu = xu_n;
    dtu_n = dtp[(size_t)(tt + 1) * DI];
    xu_n = xp[(size_t)(tt + 1) * DI];
    float dtv = h2f(dtu);
    float xv = b2f(xu);
    sd += dtv;
    float dx = dtv * xv;
    const float* bp = &Bs[tt * 16];
#pragma unroll
    for (int s = 0; s < 16; ++s) {
      float arg = dtv * As2[s];
      float dA;
      asm("v_exp_f32 %0, %1" : "=v"(dA) : "v"(arg));
      h[s] = dA * h[s] + dx * bp[s];
    }
  }

  const size_t ch = (size_t)b * DI + d;
  sumdt[ch * NC + c] = sd;
  float4* hp = (float4*)&hend[((size_t)c * CH + ch) * 16];
#pragma unroll
  for (int q = 0; q < 4; ++q)
    hp[q] = make_float4(h[q * 4], h[q * 4 + 1], h[q * 4 + 2], h[q * 4 + 3]);
}

__global__ __launch_bounds__(256) void scan_pass2(const float* __restrict__ A_log,
                                                  const float* __restrict__ sumdt,
                                                  const float* __restrict__ hend,
                                                  float* __restrict__ hstart) {
  int idx = blockIdx.x * 256 + threadIdx.x;  // ch*16 + s
  int ch = idx >> 4, s = idx & 15;
  int d = ch % DI;
  float A = -__expf(A_log[d * DS + s]);
  float h = 0.f;
  for (int c = 0; c < NC; ++c) {
    hstart[((size_t)c * CH + ch) * 16 + s] = h;
    float sd = sumdt[(size_t)ch * NC + c];
    h = __expf(A * sd) * h + hend[((size_t)c * CH + ch) * 16 + s];
  }
}

__global__ __launch_bounds__(256) void scan_pass3(const ushort* __restrict__ dt,
                                                  const ushort* __restrict__ xc,
                                                  const float* __restrict__ xd,
                                                  const ushort* __restrict__ resb,
                                                  const float* __restrict__ A_log,
                                                  const float* __restrict__ Dp,
                                                  const float* __restrict__ hstart,
                                                  float* __restrict__ out) {
  const int d = blockIdx.x * 256 + threadIdx.x;
  const int c = blockIdx.y, b = blockIdx.z;
  const int t0 = c * TC;

  __shared__ float Bs[TC * 16];  // 4 KB
  __shared__ float Cs[TC * 16];  // 4 KB
  for (int i = threadIdx.x; i < TC * 16; i += 256) {
    int tt = i >> 4, s = i & 15;
    size_t row = ((size_t)(b * L_SZ + t0 + tt)) * 80;
    Bs[i] = xd[row + DR + s];
    Cs[i] = xd[row + DR + DS + s];
  }

  float As2[16];
#pragma unroll
  for (int s = 0; s < 16; ++s)
    As2[s] = -__expf(A_log[d * DS + s]) * 1.44269504088896f;
  const float Dpv = Dp[d];

  const size_t ch = (size_t)b * DI + d;
  float h[16];
  const float4* hp = (const float4*)&hstart[((size_t)c * CH + ch) * 16];
#pragma unroll
  for (int q = 0; q < 4; ++q) {
    float4 v = hp[q];
    h[q * 4] = v.x; h[q * 4 + 1] = v.y; h[q * 4 + 2] = v.z; h[q * 4 + 3] = v.w;
  }

  __syncthreads();

  const ushort* dtp = dt + ((size_t)b * L_SZ + t0) * DI + d;
  const ushort* xp = xc + ((size_t)b * L_SZ + t0) * DI + d;
  const ushort* rp = resb + ((size_t)b * L_SZ + t0) * DI + d;
  float* op = out + ((size_t)b * L_SZ + t0) * DI + d;

  ushort dtu_n = dtp[0];
  ushort xu_n = xp[0];
  ushort ru_n = rp[0];
  for (int tt = 0; tt < TC; ++tt) {
    ushort dtu = dtu_n;
    ushort xu = xu_n;
    ushort ru = ru_n;
    dtu_n = dtp[(size_t)(tt + 1) * DI];
    xu_n = xp[(size_t)(tt + 1) * DI];
    ru_n = rp[(size_t)(tt + 1) * DI];
    float dtv = h2f(dtu);
    float xv = b2f(xu);
    float rv = b2f(ru);
    float dx = dtv * xv;
    const float* bp = &Bs[tt * 16];
    const float* cp = &Cs[tt * 16];
    float y0 = 0.f, y1 = 0.f, y2 = 0.f, y3 = 0.f;
#pragma unroll
    for (int s = 0; s < 16; s += 4) {
      float dA0, dA1, dA2, dA3;
      float a0 = dtv * As2[s], a1 = dtv * As2[s + 1], a2 = dtv * As2[s + 2], a3 = dtv * As2[s + 3];
      asm("v_exp_f32 %0, %1" : "=v"(dA0) : "v"(a0));
      asm("v_exp_f32 %0, %1" : "=v"(dA1) : "v"(a1));
      asm("v_exp_f32 %0, %1" : "=v"(dA2) : "v"(a2));
      asm("v_exp_f32 %0, %1" : "=v"(dA3) : "v"(a3));
      h[s]     = dA0 * h[s]     + dx * bp[s];
      h[s + 1] = dA1 * h[s + 1] + dx * bp[s + 1];
      h[s + 2] = dA2 * h[s + 2] + dx * bp[s + 2];
      h[s + 3] = dA3 * h[s + 3] + dx * bp[s + 3];
      y0 += h[s] * cp[s];
      y1 += h[s + 1] * cp[s + 1];
      y2 += h[s + 2] * cp[s + 2];
      y3 += h[s + 3] * cp[s + 3];
    }
    float y = (y0 + y1) + (y2 + y3);
    float sig = 1.f / (1.f + __expf(-rv));
    op[(size_t)tt * DI] = (y + xv * Dpv) * (rv * sig);
  }
}

// ---------------- launch ----------------

extern "C" void kernel_launch(void* const* d_in, const int* in_sizes, int n_in,
                              void* d_out, int out_size, void* d_ws, size_t ws_size,
                              hipStream_t stream) {
  const float* hs     = (const float*)d_in[0];
  const float* W_in   = (const float*)d_in[1];
  const float* conv_w = (const float*)d_in[2];
  const float* conv_b = (const float*)d_in[3];
  const float* W_x    = (const float*)d_in[4];
  const float* W_dt   = (const float*)d_in[5];
  const float* b_dt   = (const float*)d_in[6];
  const float* A_log  = (const float*)d_in[7];
  const float* D_par  = (const float*)d_in[8];
  float* out = (float*)d_out;
  char* ws = (char*)d_ws;

  // workspace layout (bytes).  Region [0, 80.2MB) = A1+Wt1+xpre is dead after
  // conv_silu and is re-used (aliased) for the scan scratch (hend/hstart/sumdt).
  size_t o = 0;
  ushort* A1   = (ushort*)(ws + o); o += (size_t)M_SZ * DM * 2;        // 25.2 MB
  ushort* Wt1  = (ushort*)(ws + o); o += (size_t)N1 * DM * 2;          // 4.7 MB
  ushort* xpre = (ushort*)(ws + o); o += (size_t)M_SZ * DI * 2;        // 50.3 MB
  ushort* resb = (ushort*)(ws + o); o += (size_t)M_SZ * DI * 2;        // 50.3 MB
  ushort* xcv  = (ushort*)(ws + o); o += (size_t)M_SZ * DI * 2;        // 50.3 MB
  float*  xdbl = (float*)(ws + o);  o += (size_t)M_SZ * 80 * 4;        // 5.2 MB
  ushort* dtb  = (ushort*)(ws + o); o += (size_t)M_SZ * DI * 2;        // 50.3 MB (fp16)
  float*  xdp  = (float*)(ws + o);  o += (size_t)KS * M_SZ * 80 * 4;   // 31.5 MB
  ushort* Wxb  = (ushort*)(ws + o); o += (size_t)80 * DI * 2;          // 0.25 MB
  ushort* Wdtp = (ushort*)(ws + o); o += (size_t)DI * 64 * 2;          // 0.2 MB
  if (ws_size < o) return;  // clean fail instead of OOB

  // scan scratch aliases the dead A1/Wt1/xpre region (52 MB < 80.2 MB)
  float* hend   = (float*)(ws + 0);
  float* hstart = (float*)(ws + (size_t)NC * CH * 16 * 4);             // +25.2 MB
  float* sumdt  = (float*)(ws + (size_t)2 * NC * CH * 16 * 4);         // +50.3 MB

  int n4 = M_SZ * DM / 4;
  cast_hidden<<<dim3((n4 + 255) / 256), dim3(256), 0, stream>>>((const float4*)hs, (ushort4*)A1, n4);
  transpose_w<<<dim3((3072 * 96 + 255) / 256), dim3(256), 0, stream>>>(W_in, Wt1);
  prep_small<<<dim3((80 * DI + DI * 64 + 255) / 256), dim3(256), 0, stream>>>(W_x, W_dt, Wxb, Wdtp);

  gemm_xz<<<dim3((M_SZ / 256) * (N1 / 256)), dim3(512), 0, stream>>>(A1, Wt1, xpre, resb);

  conv_silu<<<dim3(M_SZ * DI / 8 / 256), dim3(256), 0, stream>>>(xpre, conv_w, conv_b, xcv);

  xdbl_gemm<<<dim3(M_SZ / 64, KS), dim3(256), 0, stream>>>(xcv, Wxb, xdp);
  reduce_xd<<<dim3((M_SZ * 20 + 255) / 256), dim3(256), 0, stream>>>((const float4*)xdp, (float4*)xdbl);

  dt_gemm<<<dim3(M_SZ / 64, 24), dim3(256), 0, stream>>>(xdbl, Wdtp, b_dt, dtb);

  scan_pass1<<<dim3(DI / 256, NC, B_SZ), dim3(256), 0, stream>>>(dtb, xcv, xdbl, A_log, hend, sumdt);
  scan_pass2<<<dim3(CH * 16 / 256), dim3(256), 0, stream>>>(A_log, sumdt, hend, hstart);
  scan_pass3<<<dim3(DI / 256, NC, B_SZ), dim3(256), 0, stream>>>(dtb, xcv, xdbl, resb,
                                                                 A_log, D_par, hstart, out);
}

// Round 5
// 427.515 us; speedup vs baseline: 5.3808x; 1.0581x over previous
//
#include <hip/hip_runtime.h>
#include <hip/hip_bf16.h>
#include <stdint.h>

#define B_SZ 8
#define L_SZ 2048
#define DM 768
#define DI 1536
#define DS 16
#define DR 48
#define M_SZ (B_SZ * L_SZ)   // 16384
#define N1 (2 * DI)          // 3072

#define NC 32                 // chunks per sequence
#define TC (L_SZ / NC)        // 64 steps per chunk
#define CH (B_SZ * DI)        // 12288 channels
#define KS 6                  // split-K slices for xdbl
#define NT (DM / 64)          // 12 K-tiles for gemm_xz
#define L2E 1.44269504088896f

typedef short short8 __attribute__((ext_vector_type(8)));
typedef float f32x4 __attribute__((ext_vector_type(4)));
typedef float f32x2 __attribute__((ext_vector_type(2)));

__device__ __forceinline__ ushort f2b(float f) {
  __hip_bfloat16 h = __float2bfloat16(f);
  return *reinterpret_cast<ushort*>(&h);
}
__device__ __forceinline__ float b2f(ushort u) {
  __hip_bfloat16 h;
  *reinterpret_cast<ushort*>(&h) = u;
  return __bfloat162float(h);
}
__device__ __forceinline__ ushort f2h(float f) {
  _Float16 h = (_Float16)f;
  return *reinterpret_cast<ushort*>(&h);
}
__device__ __forceinline__ float h2f(ushort u) {
  _Float16 h;
  *reinterpret_cast<ushort*>(&h) = u;
  return (float)h;
}

__device__ __forceinline__ void gl16(const ushort* g, ushort* l) {
  __builtin_amdgcn_global_load_lds(
      (const __attribute__((address_space(1))) void*)g,
      (__attribute__((address_space(3))) void*)l, 16, 0, 0);
}

// ---------------- merged prep: cast hidden, transpose W_in, cast W_x, pad W_dt ------------

__global__ __launch_bounds__(256) void prep_all(const float4* __restrict__ hs4,
                                                const float* __restrict__ w_in,
                                                const float* __restrict__ wx_f,
                                                const float* __restrict__ wdt_f,
                                                ushort4* __restrict__ A1,
                                                ushort* __restrict__ wt,
                                                ushort* __restrict__ wx_b,
                                                ushort* __restrict__ wdt_p) {
  const int n4 = M_SZ * DM / 4;
  const int nT = 3072 * 96;
  const int nwx = 80 * DI;
  const int nwdt = DI * 64;
  int idx = blockIdx.x * 256 + threadIdx.x;
  if (idx < n4) {
    float4 v = hs4[idx];
    ushort4 o;
    o.x = f2b(v.x); o.y = f2b(v.y); o.z = f2b(v.z); o.w = f2b(v.w);
    A1[idx] = o;
  } else if (idx < n4 + nT) {
    int j = idx - n4;
    int n = j % 3072;
    int kb = (j / 3072) * 8;
    short8 o;
#pragma unroll
    for (int q = 0; q < 8; ++q) o[q] = (short)f2b(w_in[(size_t)(kb + q) * 3072 + n]);
    *(short8*)(wt + (size_t)n * DM + kb) = o;
  } else if (idx < n4 + nT + nwx) {
    int j = idx - n4 - nT;
    wx_b[j] = f2b(wx_f[j]);
  } else if (idx < n4 + nT + nwx + nwdt) {
    int j = idx - n4 - nT - nwx;
    int col = j >> 6, k = j & 63;
    wdt_p[j] = (k < DR) ? f2b(wdt_f[col * DR + k]) : (ushort)0;
  }
}

// ---------------- main GEMM: xz = A1(16384x768) @ W_in  (256x256 tile, 8-phase) -----------
// Fragment-major LDS (1 KB chunk = one MFMA fragment set, conflict-free ds_read_b128),
// double-buffered K-tiles, raw s_barrier, vmcnt(0) once per K-tile, setprio around MFMA.
// Epilogue: res half (bn>=DI) stores silu(res) -- the scan's gate is then a single mul.

__global__ __launch_bounds__(512, 1) void gemm_xz(const ushort* __restrict__ A,
                                                  const ushort* __restrict__ Bt,
                                                  ushort* __restrict__ xout,
                                                  ushort* __restrict__ gateout) {
  __shared__ ushort lds[65536];  // 128 KiB

  const int t = threadIdx.x;
  const int lane = t & 63;
  const int wid = t >> 6;
  const int wm = wid >> 2, wn = wid & 3;
  const int r = lane & 15, hi = lane >> 4;

  const int g = blockIdx.x;
  const int swz = (g & 7) * (768 / 8) + (g >> 3);
  const int bx = swz & 63;
  const int by = swz >> 6;
  const int bm = bx * 256;
  const int bn = by * 256;

  const bool isA = wid < 4;
  const int w4 = wid & 3;
  const ushort* gsrc[8];
  int ldso[8];
#pragma unroll
  for (int i = 0; i < 8; ++i) {
    int c = w4 * 8 + i;
    int mg = c >> 1, kkc = c & 1;
    gsrc[i] = (isA ? A + (size_t)(bm + mg * 16 + r) * DM
                   : Bt + (size_t)(bn + mg * 16 + r) * DM) + kkc * 32 + hi * 8;
    ldso[i] = (isA ? 0 : 16384) + c * 512;
  }

  f32x4 acc[8][4];
#pragma unroll
  for (int m = 0; m < 8; ++m)
#pragma unroll
    for (int n = 0; n < 4; ++n) acc[m][n] = f32x4{0.f, 0.f, 0.f, 0.f};

#pragma unroll
  for (int i = 0; i < 8; ++i) gl16(gsrc[i], &lds[ldso[i]]);
  asm volatile("s_waitcnt vmcnt(0)" ::: "memory");
  __builtin_amdgcn_s_barrier();

  for (int kt = 0; kt < NT; ++kt) {
    const int cur = kt & 1;
    const ushort* bufA = &lds[cur * 32768];
    const ushort* bufB = bufA + 16384;
    ushort* nxt = &lds[(cur ^ 1) * 32768];
    const int koff = (kt + 1) * 64;
    const bool more = (kt + 1 < NT);

    short8 afr[4][2], bfr[2][2];
#pragma unroll
    for (int q = 0; q < 4; ++q) {
      const int mq = q >> 1, nq = q & 1;
      if (nq == 0) {
#pragma unroll
        for (int m = 0; m < 4; ++m)
#pragma unroll
          for (int kk = 0; kk < 2; ++kk)
            afr[m][kk] = *(const short8*)&bufA[((wm * 8 + mq * 4 + m) * 2 + kk) * 512 + lane * 8];
      }
#pragma unroll
      for (int n = 0; n < 2; ++n)
#pragma unroll
        for (int kk = 0; kk < 2; ++kk)
          bfr[n][kk] = *(const short8*)&bufB[((wn * 4 + nq * 2 + n) * 2 + kk) * 512 + lane * 8];

      if (more) {
        gl16(gsrc[2 * q] + koff, nxt + ldso[2 * q]);
        gl16(gsrc[2 * q + 1] + koff, nxt + ldso[2 * q + 1]);
      }

      asm volatile("s_barrier" ::: "memory");

      __builtin_amdgcn_s_setprio(1);
#pragma unroll
      for (int m = 0; m < 4; ++m)
#pragma unroll
        for (int n = 0; n < 2; ++n) {
          f32x4 a = acc[mq * 4 + m][nq * 2 + n];
          a = __builtin_amdgcn_mfma_f32_16x16x32_bf16(afr[m][0], bfr[n][0], a, 0, 0, 0);
          a = __builtin_amdgcn_mfma_f32_16x16x32_bf16(afr[m][1], bfr[n][1], a, 0, 0, 0);
          acc[mq * 4 + m][nq * 2 + n] = a;
        }
      __builtin_amdgcn_s_setprio(0);

      if (q == 3) asm volatile("s_waitcnt vmcnt(0)" ::: "memory");
      asm volatile("s_barrier" ::: "memory");
    }
  }

  const bool isx = (bn < DI);
  ushort* outp = isx ? xout : gateout;
  const int cbase = bn - (isx ? 0 : DI) + wn * 64;
#pragma unroll
  for (int mf = 0; mf < 8; ++mf)
#pragma unroll
    for (int nf = 0; nf < 4; ++nf) {
      int col = cbase + nf * 16 + r;
#pragma unroll
      for (int j = 0; j < 4; ++j) {
        int row = bm + wm * 128 + mf * 16 + hi * 4 + j;
        float v = acc[mf][nf][j];
        if (!isx) v = v / (1.f + __expf(-v));  // silu(res) fused (block-uniform branch)
        outp[(size_t)row * DI + col] = f2b(v);
      }
    }
}

// ---------------- depthwise causal conv (K=4) + SiLU, 8-wide ----------------

__global__ __launch_bounds__(256) void conv_silu(const ushort* __restrict__ xp,
                                                 const float* __restrict__ cw,
                                                 const float* __restrict__ cb,
                                                 ushort* __restrict__ xc) {
  int tid = blockIdx.x * 256 + threadIdx.x;  // < M_SZ*DI/8
  const int nd = DI / 8;                     // 192
  int db = tid % nd;
  int row = tid / nd;
  int d0 = db * 8;
  int l = row & (L_SZ - 1);
  const ushort* base = xp + (size_t)row * DI + d0;
  short8 z8 = {0, 0, 0, 0, 0, 0, 0, 0};
  short8 x0 = *(const short8*)base;
  short8 xm1 = (l >= 1) ? *(const short8*)(base - DI) : z8;
  short8 xm2 = (l >= 2) ? *(const short8*)(base - 2 * DI) : z8;
  short8 xm3 = (l >= 3) ? *(const short8*)(base - 3 * DI) : z8;
  short8 o;
#pragma unroll
  for (int j = 0; j < 8; ++j) {
    float4 w = *(const float4*)(cw + (size_t)(d0 + j) * 4);
    float a = cb[d0 + j] + w.x * b2f((ushort)xm3[j]) + w.y * b2f((ushort)xm2[j]) +
              w.z * b2f((ushort)xm1[j]) + w.w * b2f((ushort)x0[j]);
    float s = a / (1.f + __expf(-a));
    o[j] = (short)f2b(s);
  }
  *(short8*)(xc + (size_t)row * DI + d0) = o;
}

// ---------------- x_dbl: split-K partials  xdp[ks][16384][80] fp32 ----------------

__global__ __launch_bounds__(256) void xdbl_gemm(const ushort* __restrict__ xc,
                                                 const ushort* __restrict__ wx,
                                                 float* __restrict__ xdp) {
  int wave = blockIdx.x * 4 + (threadIdx.x >> 6);
  int ks = blockIdx.y;
  int lane = threadIdx.x & 63;
  int r = lane & 15, hi = lane >> 4;
  int row0 = wave * 16;
  f32x4 acc[5];
#pragma unroll
  for (int n = 0; n < 5; ++n) acc[n] = f32x4{0.f, 0.f, 0.f, 0.f};
  const int kbeg = ks * (DI / KS), kend = kbeg + DI / KS;
  for (int k0 = kbeg; k0 < kend; k0 += 32) {
    short8 a = *(const short8*)(xc + (size_t)(row0 + r) * DI + k0 + hi * 8);
#pragma unroll
    for (int n = 0; n < 5; ++n) {
      short8 b = *(const short8*)(wx + (size_t)(n * 16 + r) * DI + k0 + hi * 8);
      acc[n] = __builtin_amdgcn_mfma_f32_16x16x32_bf16(a, b, acc[n], 0, 0, 0);
    }
  }
  float* op = xdp + (size_t)ks * M_SZ * 80;
#pragma unroll
  for (int n = 0; n < 5; ++n)
#pragma unroll
    for (int j = 0; j < 4; ++j)
      op[(size_t)(row0 + hi * 4 + j) * 80 + n * 16 + r] = acc[n][j];
}

__global__ __launch_bounds__(256) void reduce_xd(const float4* __restrict__ xdp,
                                                 float4* __restrict__ xd) {
  int i = blockIdx.x * 256 + threadIdx.x;
  if (i >= M_SZ * 20) return;
  float4 s = xdp[i];
#pragma unroll
  for (int k = 1; k < KS; ++k) {
    float4 v = xdp[(size_t)k * M_SZ * 20 + i];
    s.x += v.x; s.y += v.y; s.z += v.z; s.w += v.w;
  }
  xd[i] = s;
}

// ---------------- dt = softplus(x_dbl[:, :48] @ W_dt^T + b_dt) -> fp16 ----------------

__device__ __forceinline__ short8 pack8f(const float* p) {
  short8 v;
#pragma unroll
  for (int i = 0; i < 8; ++i) v[i] = (short)f2b(p[i]);
  return v;
}

__global__ __launch_bounds__(256) void dt_gemm(const float* __restrict__ xd,
                                               const ushort* __restrict__ wdtp,
                                               const float* __restrict__ bdt,
                                               ushort* __restrict__ dt) {
  int wave = blockIdx.x * 4 + (threadIdx.x >> 6);
  int lane = threadIdx.x & 63;
  int r = lane & 15, hi = lane >> 4;
  int row0 = wave * 16;
  int c0 = blockIdx.y * 64;

  float atmp[8];
  const float* ap = xd + (size_t)(row0 + r) * 80 + hi * 8;
  float4 q0 = *(const float4*)ap, q1 = *(const float4*)(ap + 4);
  atmp[0] = q0.x; atmp[1] = q0.y; atmp[2] = q0.z; atmp[3] = q0.w;
  atmp[4] = q1.x; atmp[5] = q1.y; atmp[6] = q1.z; atmp[7] = q1.w;
  short8 a0 = pack8f(atmp);
  short8 a1 = {0, 0, 0, 0, 0, 0, 0, 0};
  if (hi < 2) {
    const float* ap1 = xd + (size_t)(row0 + r) * 80 + 32 + hi * 8;
    float4 p0 = *(const float4*)ap1, p1 = *(const float4*)(ap1 + 4);
    atmp[0] = p0.x; atmp[1] = p0.y; atmp[2] = p0.z; atmp[3] = p0.w;
    atmp[4] = p1.x; atmp[5] = p1.y; atmp[6] = p1.z; atmp[7] = p1.w;
    a1 = pack8f(atmp);
  }

  f32x4 acc[4];
#pragma unroll
  for (int n = 0; n < 4; ++n) acc[n] = f32x4{0.f, 0.f, 0.f, 0.f};
#pragma unroll
  for (int n = 0; n < 4; ++n) {
    const ushort* wp = wdtp + (size_t)(c0 + n * 16 + r) * 64;
    short8 b0 = *(const short8*)(wp + hi * 8);
    short8 b1 = *(const short8*)(wp + 32 + hi * 8);
    acc[n] = __builtin_amdgcn_mfma_f32_16x16x32_bf16(a0, b0, acc[n], 0, 0, 0);
    acc[n] = __builtin_amdgcn_mfma_f32_16x16x32_bf16(a1, b1, acc[n], 0, 0, 0);
  }
#pragma unroll
  for (int n = 0; n < 4; ++n)
#pragma unroll
    for (int j = 0; j < 4; ++j) {
      int col = c0 + n * 16 + r;
      float z = acc[n][j] + bdt[col];
      float sp = (z > 20.f) ? z : __logf(1.f + __expf(z));
      dt[(size_t)(row0 + hi * 4 + j) * DI + col] = f2h(sp);
    }
}

// ---------------- chunked selective scan (f32x2-packed inner math) ----------------

__global__ __launch_bounds__(256) void scan_pass1(const ushort* __restrict__ dt,
                                                  const ushort* __restrict__ xc,
                                                  const float* __restrict__ xd,
                                                  const float* __restrict__ A_log,
                                                  float* __restrict__ hend,
                                                  float* __restrict__ sumdt) {
  const int d = blockIdx.x * 256 + threadIdx.x;
  const int c = blockIdx.y, b = blockIdx.z;
  const int t0 = c * TC;

  __shared__ float Bs[TC * 16];  // 4 KB
  for (int i = threadIdx.x; i < TC * 16; i += 256) {
    int tt = i >> 4, s = i & 15;
    Bs[i] = xd[((size_t)(b * L_SZ + t0 + tt)) * 80 + DR + s];
  }

  f32x2 a2[8];
  const float4* al4 = (const float4*)(A_log + (size_t)d * DS);
#pragma unroll
  for (int q = 0; q < 4; ++q) {
    float4 v = al4[q];
    a2[2 * q] = f32x2{-__expf(v.x) * L2E, -__expf(v.y) * L2E};
    a2[2 * q + 1] = f32x2{-__expf(v.z) * L2E, -__expf(v.w) * L2E};
  }

  __syncthreads();

  f32x2 h2[8];
#pragma unroll
  for (int s = 0; s < 8; ++s) h2[s] = f32x2{0.f, 0.f};
  float sd = 0.f;

  const ushort* dtp = dt + ((size_t)b * L_SZ + t0) * DI + d;
  const ushort* xp = xc + ((size_t)b * L_SZ + t0) * DI + d;

  ushort dtu_n = dtp[0];
  ushort xu_n = xp[0];
  for (int tt = 0; tt < TC; ++tt) {
    ushort dtu = dtu_n;
    ushort xu = xu_n;
    dtu_n = dtp[(size_t)(tt + 1) * DI];  // one-past-end lands in adjacent ws buffer
    xu_n = xp[(size_t)(tt + 1) * DI];
    float dtv = h2f(dtu);
    float xv = b2f(xu);
    sd += dtv;
    float dx = dtv * xv;
    f32x2 dt2 = f32x2{dtv, dtv};
    f32x2 dx2 = f32x2{dx, dx};
    const f32x2* bp2 = (const f32x2*)&Bs[tt * 16];
#pragma unroll
    for (int sp = 0; sp < 8; ++sp) {
      f32x2 arg = dt2 * a2[sp];
      float e0, e1;
      asm("v_exp_f32 %0, %1" : "=v"(e0) : "v"(arg[0]));
      asm("v_exp_f32 %0, %1" : "=v"(e1) : "v"(arg[1]));
      f32x2 dA = f32x2{e0, e1};
      h2[sp] = dA * h2[sp] + dx2 * bp2[sp];
    }
  }

  const size_t ch = (size_t)b * DI + d;
  sumdt[ch * NC + c] = sd;
  float4* hp = (float4*)&hend[((size_t)c * CH + ch) * 16];
#pragma unroll
  for (int q = 0; q < 4; ++q)
    hp[q] = make_float4(h2[2 * q][0], h2[2 * q][1], h2[2 * q + 1][0], h2[2 * q + 1][1]);
}

__global__ __launch_bounds__(256) void scan_pass2(const float* __restrict__ A_log,
                                                  const float* __restrict__ sumdt,
                                                  const float* __restrict__ hend,
                                                  float* __restrict__ hstart) {
  int idx = blockIdx.x * 256 + threadIdx.x;  // ch*16 + s
  int ch = idx >> 4, s = idx & 15;
  int d = ch % DI;
  float A = -__expf(A_log[d * DS + s]);
  float h = 0.f;
  for (int c = 0; c < NC; ++c) {
    hstart[((size_t)c * CH + ch) * 16 + s] = h;
    float sd = sumdt[(size_t)ch * NC + c];
    h = __expf(A * sd) * h + hend[((size_t)c * CH + ch) * 16 + s];
  }
}

__global__ __launch_bounds__(256) void scan_pass3(const ushort* __restrict__ dt,
                                                  const ushort* __restrict__ xc,
                                                  const float* __restrict__ xd,
                                                  const ushort* __restrict__ gateb,
                                                  const float* __restrict__ A_log,
                                                  const float* __restrict__ Dp,
                                                  const float* __restrict__ hstart,
                                                  float* __restrict__ out) {
  const int d = blockIdx.x * 256 + threadIdx.x;
  const int c = blockIdx.y, b = blockIdx.z;
  const int t0 = c * TC;

  __shared__ float Bs[TC * 16];  // 4 KB
  __shared__ float Cs[TC * 16];  // 4 KB
  for (int i = threadIdx.x; i < TC * 16; i += 256) {
    int tt = i >> 4, s = i & 15;
    size_t row = ((size_t)(b * L_SZ + t0 + tt)) * 80;
    Bs[i] = xd[row + DR + s];
    Cs[i] = xd[row + DR + DS + s];
  }

  f32x2 a2[8];
  const float4* al4 = (const float4*)(A_log + (size_t)d * DS);
#pragma unroll
  for (int q = 0; q < 4; ++q) {
    float4 v = al4[q];
    a2[2 * q] = f32x2{-__expf(v.x) * L2E, -__expf(v.y) * L2E};
    a2[2 * q + 1] = f32x2{-__expf(v.z) * L2E, -__expf(v.w) * L2E};
  }
  const float Dpv = Dp[d];

  const size_t ch = (size_t)b * DI + d;
  f32x2 h2[8];
  const float4* hp = (const float4*)&hstart[((size_t)c * CH + ch) * 16];
#pragma unroll
  for (int q = 0; q < 4; ++q) {
    float4 v = hp[q];
    h2[2 * q] = f32x2{v.x, v.y};
    h2[2 * q + 1] = f32x2{v.z, v.w};
  }

  __syncthreads();

  const ushort* dtp = dt + ((size_t)b * L_SZ + t0) * DI + d;
  const ushort* xp = xc + ((size_t)b * L_SZ + t0) * DI + d;
  const ushort* gp = gateb + ((size_t)b * L_SZ + t0) * DI + d;
  float* op = out + ((size_t)b * L_SZ + t0) * DI + d;

  ushort dtu_n = dtp[0];
  ushort xu_n = xp[0];
  ushort gu_n = gp[0];
  for (int tt = 0; tt < TC; ++tt) {
    ushort dtu = dtu_n;
    ushort xu = xu_n;
    ushort gu = gu_n;
    dtu_n = dtp[(size_t)(tt + 1) * DI];
    xu_n = xp[(size_t)(tt + 1) * DI];
    gu_n = gp[(size_t)(tt + 1) * DI];
    float dtv = h2f(dtu);
    float xv = b2f(xu);
    float gv = b2f(gu);  // pre-computed silu(res)
    float dx = dtv * xv;
    f32x2 dt2 = f32x2{dtv, dtv};
    f32x2 dx2 = f32x2{dx, dx};
    const f32x2* bp2 = (const f32x2*)&Bs[tt * 16];
    const f32x2* cp2 = (const f32x2*)&Cs[tt * 16];
    f32x2 ya = f32x2{0.f, 0.f}, yb = f32x2{0.f, 0.f};
#pragma unroll
    for (int sp = 0; sp < 8; sp += 2) {
      f32x2 arg0 = dt2 * a2[sp];
      f32x2 arg1 = dt2 * a2[sp + 1];
      float e0, e1, e2, e3;
      asm("v_exp_f32 %0, %1" : "=v"(e0) : "v"(arg0[0]));
      asm("v_exp_f32 %0, %1" : "=v"(e1) : "v"(arg0[1]));
      asm("v_exp_f32 %0, %1" : "=v"(e2) : "v"(arg1[0]));
      asm("v_exp_f32 %0, %1" : "=v"(e3) : "v"(arg1[1]));
      f32x2 dA0 = f32x2{e0, e1};
      f32x2 dA1 = f32x2{e2, e3};
      h2[sp] = dA0 * h2[sp] + dx2 * bp2[sp];
      h2[sp + 1] = dA1 * h2[sp + 1] + dx2 * bp2[sp + 1];
      ya = ya + h2[sp] * cp2[sp];
      yb = yb + h2[sp + 1] * cp2[sp + 1];
    }
    f32x2 ys = ya + yb;
    float y = ys[0] + ys[1];
    op[(size_t)tt * DI] = (y + xv * Dpv) * gv;
  }
}

// ---------------- launch ----------------

extern "C" void kernel_launch(void* const* d_in, const int* in_sizes, int n_in,
                              void* d_out, int out_size, void* d_ws, size_t ws_size,
                              hipStream_t stream) {
  const float* hs     = (const float*)d_in[0];
  const float* W_in   = (const float*)d_in[1];
  const float* conv_w = (const float*)d_in[2];
  const float* conv_b = (const float*)d_in[3];
  const float* W_x    = (const float*)d_in[4];
  const float* W_dt   = (const float*)d_in[5];
  const float* b_dt   = (const float*)d_in[6];
  const float* A_log  = (const float*)d_in[7];
  const float* D_par  = (const float*)d_in[8];
  float* out = (float*)d_out;
  char* ws = (char*)d_ws;

  // workspace layout (bytes).  Region [0, 80.2MB) = A1+Wt1+xpre is dead after
  // conv_silu and is re-used (aliased) for the scan scratch (hend/hstart/sumdt).
  size_t o = 0;
  ushort* A1   = (ushort*)(ws + o); o += (size_t)M_SZ * DM * 2;        // 25.2 MB
  ushort* Wt1  = (ushort*)(ws + o); o += (size_t)N1 * DM * 2;          // 4.7 MB
  ushort* xpre = (ushort*)(ws + o); o += (size_t)M_SZ * DI * 2;        // 50.3 MB
  ushort* gate = (ushort*)(ws + o); o += (size_t)M_SZ * DI * 2;        // 50.3 MB (silu(res))
  ushort* xcv  = (ushort*)(ws + o); o += (size_t)M_SZ * DI * 2;        // 50.3 MB
  float*  xdbl = (float*)(ws + o);  o += (size_t)M_SZ * 80 * 4;        // 5.2 MB
  ushort* dtb  = (ushort*)(ws + o); o += (size_t)M_SZ * DI * 2;        // 50.3 MB (fp16)
  float*  xdp  = (float*)(ws + o);  o += (size_t)KS * M_SZ * 80 * 4;   // 31.5 MB
  ushort* Wxb  = (ushort*)(ws + o); o += (size_t)80 * DI * 2;          // 0.25 MB
  ushort* Wdtp = (ushort*)(ws + o); o += (size_t)DI * 64 * 2;          // 0.2 MB
  if (ws_size < o) return;  // clean fail instead of OOB

  // scan scratch aliases the dead A1/Wt1/xpre region (52 MB < 80.2 MB)
  float* hend   = (float*)(ws + 0);
  float* hstart = (float*)(ws + (size_t)NC * CH * 16 * 4);             // +25.2 MB
  float* sumdt  = (float*)(ws + (size_t)2 * NC * CH * 16 * 4);         // +50.3 MB

  const int nprep = M_SZ * DM / 4 + 3072 * 96 + 80 * DI + DI * 64;
  prep_all<<<dim3((nprep + 255) / 256), dim3(256), 0, stream>>>(
      (const float4*)hs, W_in, W_x, W_dt, (ushort4*)A1, Wt1, Wxb, Wdtp);

  gemm_xz<<<dim3((M_SZ / 256) * (N1 / 256)), dim3(512), 0, stream>>>(A1, Wt1, xpre, gate);

  conv_silu<<<dim3(M_SZ * DI / 8 / 256), dim3(256), 0, stream>>>(xpre, conv_w, conv_b, xcv);

  xdbl_gemm<<<dim3(M_SZ / 64, KS), dim3(256), 0, stream>>>(xcv, Wxb, xdp);
  reduce_xd<<<dim3((M_SZ * 20 + 255) / 256), dim3(256), 0, stream>>>((const float4*)xdp, (float4*)xdbl);

  dt_gemm<<<dim3(M_SZ / 64, 24), dim3(256), 0, stream>>>(xdbl, Wdtp, b_dt, dtb);

  scan_pass1<<<dim3(DI / 256, NC, B_SZ), dim3(256), 0, stream>>>(dtb, xcv, xdbl, A_log, hend, sumdt);
  scan_pass2<<<dim3(CH * 16 / 256), dim3(256), 0, stream>>>(A_log, sumdt, hend, hstart);
  scan_pass3<<<dim3(DI / 256, NC, B_SZ), dim3(256), 0, stream>>>(dtb, xcv, xdbl, gate,
                                                                 A_log, D_par, hstart, out);
}